// Round 6
// baseline (2190.205 us; speedup 1.0000x reference)
//
#include <hip/hip_runtime.h>
#include <hip/hip_bf16.h>

// DetProposalVGHead on MI355X.
// fused = [v, p, v*p, v-p]  =>  fused@W1 = v@(Wa+Wd) + p@(Wb-Wd) + (v*p)@Wc
// (never materialize the [B,P,N,4R] fused tensor).
//
// Round-5 was GREEN: fp64 ranking chain + EPS=2.5e-7 tie-window (tie -> lowest
// index) reproduces the reference's top-k exactly.
// Round-6 (perf, semantics preserved):
//  * fp32 chain (validated pair_gemm) computes o_sim/o_reg AND a per-row
//    fp32 top-32 candidate superset; the fp64 pair GEMM rescans only those
//    2048 candidate pairs (1/8 the fp64 work), then the IDENTICAL fp64+EPS
//    top-k runs on the candidates. vis64/Xv64 stay fp64.
//  * fp64 GEMM LDS bank-conflict fix: B-fragment read mapping tx+16*j
//    (conflict-free) + As[16][65] padding (write conflicts gone).

namespace {

constexpr int Nc_   = 256;    // boxes
constexpr int Dc    = 2048;
constexpr int Rc    = 1024;
constexpr int TOPN  = 16;
constexpr int NCAND = 32;     // fp32 prescreen candidates per row
constexpr int HS    = 256;    // per-head hidden width
constexpr int HO    = 512;    // combined (sim|reg) hidden, stage-2 only
constexpr int BPc   = 64;     // B*P
constexpr int PAIRS1 = 16384; // B*P*N
constexpr int PAIRS2 = 1024;  // B*P*topN
constexpr int CPAIRS = BPc * NCAND; // 2048

__device__ __forceinline__ float  leaky01f(float x)  { return x > 0.f ? x : 0.01f * x; }
__device__ __forceinline__ double leaky01d(double x) { return x > 0.0 ? x : 0.01  * x; }

// ---------------------------------------------------------------------------
// fp64-accumulate GEMM: C = act(A @ W + bias). BM=BN=64, BK=16, TM=TN=4.
// Conflict-free: As padded [16][65]; B fragment read at tx+16*j.
// ---------------------------------------------------------------------------
template <typename TA, typename TW, bool ST64, bool ST32, bool LEAKY>
__global__ __launch_bounds__(256) void dgemm64_kernel(
    const TA* __restrict__ A, const TW* __restrict__ W, const float* __restrict__ bias,
    double* __restrict__ C64, float* __restrict__ C32, int M, int N, int K)
{
  __shared__ double As[16][65];
  __shared__ double Bs[16][64];
  const int t = threadIdx.x, tx = t & 15, ty = t >> 4;
  const int row0 = blockIdx.y * 64, col0 = blockIdx.x * 64;
  double acc[4][4] = {};

  for (int k0 = 0; k0 < K; k0 += 16) {
    {
      int mm = t >> 2, kq = (t & 3) * 4;
      const TA* src = A + (size_t)(row0 + mm) * K + k0 + kq;
      double v0, v1, v2, v3;
      if constexpr (sizeof(TA) == 4) {
        float4 f = *(const float4*)src; v0 = f.x; v1 = f.y; v2 = f.z; v3 = f.w;
      } else {
        const double2* d = (const double2*)src;
        double2 a = d[0], b = d[1]; v0 = a.x; v1 = a.y; v2 = b.x; v3 = b.y;
      }
      As[kq + 0][mm] = v0; As[kq + 1][mm] = v1; As[kq + 2][mm] = v2; As[kq + 3][mm] = v3;
    }
    {
      int kk = t >> 4, nq = (t & 15) * 4;
      const TW* src = W + (size_t)(k0 + kk) * N + col0 + nq;
      if constexpr (sizeof(TW) == 4) {
        float4 f = *(const float4*)src;
        Bs[kk][nq] = f.x; Bs[kk][nq + 1] = f.y; Bs[kk][nq + 2] = f.z; Bs[kk][nq + 3] = f.w;
      } else {
        const double2* d = (const double2*)src;
        double2 a = d[0], b = d[1];
        Bs[kk][nq] = a.x; Bs[kk][nq + 1] = a.y; Bs[kk][nq + 2] = b.x; Bs[kk][nq + 3] = b.y;
      }
    }
    __syncthreads();
#pragma unroll
    for (int kk = 0; kk < 16; ++kk) {
      double a[4], b[4];
#pragma unroll
      for (int i = 0; i < 4; ++i) a[i] = As[kk][ty * 4 + i];
#pragma unroll
      for (int j = 0; j < 4; ++j) b[j] = Bs[kk][tx + 16 * j];
#pragma unroll
      for (int i = 0; i < 4; ++i)
#pragma unroll
        for (int j = 0; j < 4; ++j) acc[i][j] = fma(a[i], b[j], acc[i][j]);
    }
    __syncthreads();
  }

#pragma unroll
  for (int i = 0; i < 4; ++i) {
    int r = row0 + ty * 4 + i;
#pragma unroll
    for (int j = 0; j < 4; ++j) {
      int c = col0 + tx + 16 * j;
      double v = acc[i][j];
      if (bias) v += (double)bias[c];
      if constexpr (LEAKY) v = leaky01d(v);
      if constexpr (ST64) C64[(size_t)r * N + c] = v;
      if constexpr (ST32) C32[(size_t)r * N + c] = (float)v;
    }
  }
}

// ---------------------------------------------------------------------------
// fp64 candidate pair GEMM: H[m,c] = leaky((vis64[vr]*phr[pr])@W + Xv + Xp + b1)
// m in [0, CPAIRS): bp = m>>5, n = candn[m], vr = (bp>>4)*256 + n, pr = bp.
// ---------------------------------------------------------------------------
__global__ __launch_bounds__(256) void pair64c_kernel(
    const double* __restrict__ vis, const float* __restrict__ phr,
    const double* __restrict__ W, const double* __restrict__ Xv,
    const double* __restrict__ Xp, const double* __restrict__ b1,
    const int* __restrict__ candn, double* __restrict__ H)
{
  __shared__ double As[16][65];
  __shared__ double Bs[16][64];
  const int t = threadIdx.x, tx = t & 15, ty = t >> 4;
  const int row0 = blockIdx.y * 64, col0 = blockIdx.x * 64;
  double acc[4][4] = {};

  // loop-invariant indirection for the staging row this thread loads
  const int mm = t >> 2, kq = (t & 3) * 4;
  const int ms = row0 + mm, bps = ms >> 5;
  const int vrs = ((bps >> 4) << 8) | candn[ms], prs = bps;

  for (int k0 = 0; k0 < Rc; k0 += 16) {
    {
      const double2* vd = (const double2*)(vis + (size_t)vrs * Rc + k0 + kq);
      double2 a = vd[0], b = vd[1];
      float4 p = *(const float4*)(phr + (size_t)prs * Rc + k0 + kq);
      As[kq + 0][mm] = a.x * (double)p.x; As[kq + 1][mm] = a.y * (double)p.y;
      As[kq + 2][mm] = b.x * (double)p.z; As[kq + 3][mm] = b.y * (double)p.w;
    }
    {
      int kk = t >> 4, nq = (t & 15) * 4;
      const double2* d = (const double2*)(W + (size_t)(k0 + kk) * HS + col0 + nq);
      double2 a = d[0], b = d[1];
      Bs[kk][nq] = a.x; Bs[kk][nq + 1] = a.y; Bs[kk][nq + 2] = b.x; Bs[kk][nq + 3] = b.y;
    }
    __syncthreads();
#pragma unroll
    for (int kk = 0; kk < 16; ++kk) {
      double a[4], b[4];
#pragma unroll
      for (int i = 0; i < 4; ++i) a[i] = As[kk][ty * 4 + i];
#pragma unroll
      for (int j = 0; j < 4; ++j) b[j] = Bs[kk][tx + 16 * j];
#pragma unroll
      for (int i = 0; i < 4; ++i)
#pragma unroll
        for (int j = 0; j < 4; ++j) acc[i][j] = fma(a[i], b[j], acc[i][j]);
    }
    __syncthreads();
  }

#pragma unroll
  for (int i = 0; i < 4; ++i) {
    int r = row0 + ty * 4 + i, bp = r >> 5;
    int vr = ((bp >> 4) << 8) | candn[r], pr = bp;
#pragma unroll
    for (int j = 0; j < 4; ++j) {
      int c = col0 + tx + 16 * j;
      double v = acc[i][j] + Xv[(size_t)vr * HS + c] + Xp[(size_t)pr * HS + c] + b1[c];
      H[(size_t)r * HS + c] = leaky01d(v);
    }
  }
}

// ---------------------------------------------------------------------------
// fp32 tiled GEMM: C = act(A@W + bias).
// ---------------------------------------------------------------------------
template <int BM, int BN, int BK, int TM, int TN>
__global__ __launch_bounds__(256) void sgemm_kernel(
    const float* __restrict__ A, const float* __restrict__ W,
    const float* __restrict__ bias, float* __restrict__ C,
    int M, int Nc, int K, int leaky)
{
  constexpr int THREADS = (BM / TM) * (BN / TN);
  static_assert(THREADS == 256, "block must be 256");
  __shared__ float As[BK][BM];
  __shared__ float Bs[BK][BN];

  const int t = threadIdx.x;
  const int tx = t % (BN / TN), ty = t / (BN / TN);
  const int row0 = blockIdx.y * BM, col0 = blockIdx.x * BN;
  float acc[TM][TN] = {};

  for (int k0 = 0; k0 < K; k0 += BK) {
    constexpr int AV = BM * BK / 4 / THREADS;
#pragma unroll
    for (int p_ = 0; p_ < AV; ++p_) {
      int f = p_ * THREADS + t;
      int mm = f / (BK / 4), kq = (f % (BK / 4)) * 4;
      float4 a4 = *(const float4*)(A + (size_t)(row0 + mm) * K + k0 + kq);
      As[kq + 0][mm] = a4.x; As[kq + 1][mm] = a4.y;
      As[kq + 2][mm] = a4.z; As[kq + 3][mm] = a4.w;
    }
    constexpr int BV = BK * BN / 4 / THREADS;
#pragma unroll
    for (int p_ = 0; p_ < BV; ++p_) {
      int f = p_ * THREADS + t;
      int nq = (f % (BN / 4)) * 4, kk = f / (BN / 4);
      *(float4*)&Bs[kk][nq] = *(const float4*)(W + (size_t)(k0 + kk) * Nc + col0 + nq);
    }
    __syncthreads();
#pragma unroll
    for (int kk = 0; kk < BK; ++kk) {
      float a[TM], bb[TN];
#pragma unroll
      for (int i = 0; i < TM; i += 4) {
        float4 v = *(const float4*)&As[kk][ty * TM + i];
        a[i] = v.x; a[i + 1] = v.y; a[i + 2] = v.z; a[i + 3] = v.w;
      }
#pragma unroll
      for (int j = 0; j < TN; j += 4) {
        float4 v = *(const float4*)&Bs[kk][tx * TN + j];
        bb[j] = v.x; bb[j + 1] = v.y; bb[j + 2] = v.z; bb[j + 3] = v.w;
      }
#pragma unroll
      for (int i = 0; i < TM; ++i)
#pragma unroll
        for (int j = 0; j < TN; ++j) acc[i][j] = fmaf(a[i], bb[j], acc[i][j]);
    }
    __syncthreads();
  }

#pragma unroll
  for (int i = 0; i < TM; ++i) {
    int r = row0 + ty * TM + i;
#pragma unroll
    for (int j = 0; j < TN; j += 4) {
      int c = col0 + tx * TN + j;
      float4 o;
      o.x = acc[i][j]; o.y = acc[i][j + 1]; o.z = acc[i][j + 2]; o.w = acc[i][j + 3];
      if (bias) {
        float4 bv = *(const float4*)(bias + c);
        o.x += bv.x; o.y += bv.y; o.z += bv.z; o.w += bv.w;
      }
      if (leaky) { o.x = leaky01f(o.x); o.y = leaky01f(o.y); o.z = leaky01f(o.z); o.w = leaky01f(o.w); }
      *(float4*)(C + (size_t)r * Nc + c) = o;
    }
  }
}

// ---------------------------------------------------------------------------
// fp32 pair GEMM. TVIS = float|double (casts on load).
// ---------------------------------------------------------------------------
template <int BM, int BN, int BK, int TM, int TN, int STAGE, int NCOL, typename TVIS>
__global__ __launch_bounds__(256) void pair_gemm_kernel(
    const TVIS* __restrict__ vis, const float* __restrict__ phr,
    const float* __restrict__ Wvp, const float* __restrict__ Xv,
    const float* __restrict__ Xp, const float* __restrict__ b1c,
    float* __restrict__ Hout, int M)
{
  constexpr int THREADS = (BM / TM) * (BN / TN);
  static_assert(THREADS == 256, "block must be 256");
  __shared__ float As[BK][BM];
  __shared__ float Bs[BK][BN];

  const int t = threadIdx.x;
  const int tx = t % (BN / TN), ty = t / (BN / TN);
  const int row0 = blockIdx.y * BM, col0 = blockIdx.x * BN;
  float acc[TM][TN] = {};

  for (int k0 = 0; k0 < Rc; k0 += BK) {
    constexpr int AV = BM * BK / 4 / THREADS;
#pragma unroll
    for (int p_ = 0; p_ < AV; ++p_) {
      int f = p_ * THREADS + t;
      int mm = f / (BK / 4), kq = (f % (BK / 4)) * 4;
      int m = row0 + mm;
      int vr, pr;
      if (STAGE == 1) { int bp = m >> 8; pr = bp; vr = ((bp >> 4) << 8) | (m & 255); }
      else            { vr = m; pr = m >> 4; }
      float4 v4;
      if constexpr (sizeof(TVIS) == 8) {
        const double2* d = (const double2*)(vis + (size_t)vr * Rc + k0 + kq);
        double2 a = d[0], b = d[1];
        v4 = make_float4((float)a.x, (float)a.y, (float)b.x, (float)b.y);
      } else {
        v4 = *(const float4*)((const float*)vis + (size_t)vr * Rc + k0 + kq);
      }
      float4 p4 = *(const float4*)(phr + (size_t)pr * Rc + k0 + kq);
      As[kq + 0][mm] = v4.x * p4.x; As[kq + 1][mm] = v4.y * p4.y;
      As[kq + 2][mm] = v4.z * p4.z; As[kq + 3][mm] = v4.w * p4.w;
    }
    constexpr int BV = BK * BN / 4 / THREADS;
#pragma unroll
    for (int p_ = 0; p_ < BV; ++p_) {
      int f = p_ * THREADS + t;
      int nq = (f % (BN / 4)) * 4, kk = f / (BN / 4);
      *(float4*)&Bs[kk][nq] = *(const float4*)(Wvp + (size_t)(k0 + kk) * NCOL + col0 + nq);
    }
    __syncthreads();
#pragma unroll
    for (int kk = 0; kk < BK; ++kk) {
      float a[TM], bb[TN];
#pragma unroll
      for (int i = 0; i < TM; i += 4) {
        float4 v = *(const float4*)&As[kk][ty * TM + i];
        a[i] = v.x; a[i + 1] = v.y; a[i + 2] = v.z; a[i + 3] = v.w;
      }
#pragma unroll
      for (int j = 0; j < TN; j += 4) {
        float4 v = *(const float4*)&Bs[kk][tx * TN + j];
        bb[j] = v.x; bb[j + 1] = v.y; bb[j + 2] = v.z; bb[j + 3] = v.w;
      }
#pragma unroll
      for (int i = 0; i < TM; ++i)
#pragma unroll
        for (int j = 0; j < TN; ++j) acc[i][j] = fmaf(a[i], bb[j], acc[i][j]);
    }
    __syncthreads();
  }

#pragma unroll
  for (int i = 0; i < TM; ++i) {
    int r = row0 + ty * TM + i;
    int vr, pr;
    if (STAGE == 1) { int bp = r >> 8; pr = bp; vr = ((bp >> 4) << 8) | (r & 255); }
    else            { vr = r; pr = r >> 4; }
#pragma unroll
    for (int j = 0; j < TN; j += 4) {
      int c = col0 + tx * TN + j;
      float4 xv = *(const float4*)(Xv + (size_t)vr * NCOL + c);
      float4 xp = *(const float4*)(Xp + (size_t)pr * NCOL + c);
      float4 bv = *(const float4*)(b1c + c);
      float4 o;
      o.x = leaky01f(acc[i][j]     + xv.x + xp.x + bv.x);
      o.y = leaky01f(acc[i][j + 1] + xv.y + xp.y + bv.y);
      o.z = leaky01f(acc[i][j + 2] + xv.z + xp.z + bv.z);
      o.w = leaky01f(acc[i][j + 3] + xv.w + xp.w + bv.w);
      *(float4*)(Hout + (size_t)r * NCOL + c) = o;
    }
  }
}

// --- weight prep -----------------------------------------------------------
__global__ __launch_bounds__(256) void prep_sim64_kernel(
    const float* __restrict__ w1, const float* __restrict__ b1,
    double* __restrict__ Wv, double* __restrict__ Wp, double* __restrict__ Wvp,
    double* __restrict__ bO)
{
  int idx = blockIdx.x * 256 + threadIdx.x;  // Rc*HS = 262144
  int r = idx >> 8, c = idx & 255;
  double wa = (double)w1[(size_t)(0 * Rc + r) * 256 + c];
  double wb = (double)w1[(size_t)(1 * Rc + r) * 256 + c];
  double wc = (double)w1[(size_t)(2 * Rc + r) * 256 + c];
  double wd = (double)w1[(size_t)(3 * Rc + r) * 256 + c];
  Wv[idx] = wa + wd; Wp[idx] = wb - wd; Wvp[idx] = wc;
  if (r == 0) bO[c] = (double)b1[c];
}

// fp32 per-head prep (used for sim AND reg heads)
__global__ __launch_bounds__(256) void prep_head32_kernel(
    const float* __restrict__ w1, const float* __restrict__ b1,
    float* __restrict__ Wv, float* __restrict__ Wp, float* __restrict__ Wvp,
    float* __restrict__ bO)
{
  int idx = blockIdx.x * 256 + threadIdx.x;
  int r = idx >> 8, c = idx & 255;
  float wa = w1[(size_t)(0 * Rc + r) * 256 + c];
  float wb = w1[(size_t)(1 * Rc + r) * 256 + c];
  float wc = w1[(size_t)(2 * Rc + r) * 256 + c];
  float wd = w1[(size_t)(3 * Rc + r) * 256 + c];
  Wv[idx] = wa + wd; Wp[idx] = wb - wd; Wvp[idx] = wc;
  if (r == 0) bO[c] = b1[c];
}

__global__ __launch_bounds__(256) void prep_t_kernel(
    const float* __restrict__ simw1, const float* __restrict__ regw1,
    const float* __restrict__ simb1, const float* __restrict__ regb1,
    float* __restrict__ Wv, float* __restrict__ Wp, float* __restrict__ Wvp,
    float* __restrict__ b1c)
{
  int idx = blockIdx.x * 256 + threadIdx.x;  // Rc*HO = 524288
  int r = idx >> 9, j = idx & (HO - 1);
  const float* w1 = (j < 256) ? simw1 : regw1;
  int c = j & 255;
  float wa = w1[(size_t)(0 * Rc + r) * 256 + c];
  float wb = w1[(size_t)(1 * Rc + r) * 256 + c];
  float wc = w1[(size_t)(2 * Rc + r) * 256 + c];
  float wd = w1[(size_t)(3 * Rc + r) * 256 + c];
  Wv[idx] = wa + wd; Wp[idx] = wb - wd; Wvp[idx] = wc;
  if (r == 0) b1c[j] = (j < 256) ? simb1[c] : regb1[c];
}

// --- second layers ---------------------------------------------------------
__global__ __launch_bounds__(256) void layer2_sim32_kernel(
    const float* __restrict__ h, const float* __restrict__ sw2,
    const float* __restrict__ sb2, float* __restrict__ out, int M)
{
  int wave = (blockIdx.x * blockDim.x + threadIdx.x) >> 6, lane = threadIdx.x & 63;
  if (wave >= M) return;
  float4 hv = *(const float4*)(h + (size_t)wave * HS + lane * 4);
  float4 wv = *(const float4*)(sw2 + lane * 4);
  float s = hv.x * wv.x + hv.y * wv.y + hv.z * wv.z + hv.w * wv.w;
#pragma unroll
  for (int off = 32; off; off >>= 1) s += __shfl_xor(s, off);
  if (lane == 0) out[wave] = s + sb2[0];
}

__global__ __launch_bounds__(256) void layer2_sim64_kernel(
    const double* __restrict__ h, const float* __restrict__ sw2,
    const float* __restrict__ sb2, double* __restrict__ out, int M)
{
  int wave = (blockIdx.x * blockDim.x + threadIdx.x) >> 6, lane = threadIdx.x & 63;
  if (wave >= M) return;
  const double* hr = h + (size_t)wave * HS + lane * 4;
  double2 h0 = *(const double2*)hr, h1 = *(const double2*)(hr + 2);
  float4 w = *(const float4*)(sw2 + lane * 4);
  double s = h0.x * (double)w.x + h0.y * (double)w.y + h1.x * (double)w.z + h1.y * (double)w.w;
#pragma unroll
  for (int off = 32; off; off >>= 1) s += __shfl_xor(s, off);
  if (lane == 0) out[wave] = s + (double)sb2[0];
}

__global__ __launch_bounds__(256) void layer2_reg32_kernel(
    const float* __restrict__ h, const float* __restrict__ rw2,
    const float* __restrict__ rb2, float* __restrict__ reg_out, int M)
{
  int wave = (blockIdx.x * blockDim.x + threadIdx.x) >> 6, lane = threadIdx.x & 63;
  if (wave >= M) return;
  float4 hr = *(const float4*)(h + (size_t)wave * HS + lane * 4);
  float4 r0 = *(const float4*)(rw2 + (size_t)(lane * 4 + 0) * 4);
  float4 r1 = *(const float4*)(rw2 + (size_t)(lane * 4 + 1) * 4);
  float4 r2 = *(const float4*)(rw2 + (size_t)(lane * 4 + 2) * 4);
  float4 r3 = *(const float4*)(rw2 + (size_t)(lane * 4 + 3) * 4);
  float c0 = hr.x * r0.x + hr.y * r1.x + hr.z * r2.x + hr.w * r3.x;
  float c1 = hr.x * r0.y + hr.y * r1.y + hr.z * r2.y + hr.w * r3.y;
  float c2 = hr.x * r0.z + hr.y * r1.z + hr.z * r2.z + hr.w * r3.z;
  float c3 = hr.x * r0.w + hr.y * r1.w + hr.z * r2.w + hr.w * r3.w;
#pragma unroll
  for (int off = 32; off; off >>= 1) {
    c0 += __shfl_xor(c0, off); c1 += __shfl_xor(c1, off);
    c2 += __shfl_xor(c2, off); c3 += __shfl_xor(c3, off);
  }
  if (lane == 0) {
    float4 o; o.x = c0 + rb2[0]; o.y = c1 + rb2[1]; o.z = c2 + rb2[2]; o.w = c3 + rb2[3];
    *(float4*)(reg_out + (size_t)wave * 4) = o;
  }
}

__global__ __launch_bounds__(256) void layer2_t_kernel(
    const float* __restrict__ hidden,
    const float* __restrict__ sw2, const float* __restrict__ sb2,
    const float* __restrict__ rw2, const float* __restrict__ rb2,
    float* __restrict__ sim_logits, float* __restrict__ reg_out, int M)
{
  int wave = (blockIdx.x * blockDim.x + threadIdx.x) >> 6, lane = threadIdx.x & 63;
  if (wave >= M) return;
  const float* h = hidden + (size_t)wave * HO;
  float4 hs = *(const float4*)(h + lane * 4);
  float4 hr = *(const float4*)(h + 256 + lane * 4);
  float4 ws = *(const float4*)(sw2 + lane * 4);
  float s = hs.x * ws.x + hs.y * ws.y + hs.z * ws.z + hs.w * ws.w;
  float4 r0 = *(const float4*)(rw2 + (size_t)(lane * 4 + 0) * 4);
  float4 r1 = *(const float4*)(rw2 + (size_t)(lane * 4 + 1) * 4);
  float4 r2 = *(const float4*)(rw2 + (size_t)(lane * 4 + 2) * 4);
  float4 r3 = *(const float4*)(rw2 + (size_t)(lane * 4 + 3) * 4);
  float c0 = hr.x * r0.x + hr.y * r1.x + hr.z * r2.x + hr.w * r3.x;
  float c1 = hr.x * r0.y + hr.y * r1.y + hr.z * r2.y + hr.w * r3.y;
  float c2 = hr.x * r0.z + hr.y * r1.z + hr.z * r2.z + hr.w * r3.z;
  float c3 = hr.x * r0.w + hr.y * r1.w + hr.z * r2.w + hr.w * r3.w;
#pragma unroll
  for (int off = 32; off; off >>= 1) {
    s  += __shfl_xor(s, off);
    c0 += __shfl_xor(c0, off); c1 += __shfl_xor(c1, off);
    c2 += __shfl_xor(c2, off); c3 += __shfl_xor(c3, off);
  }
  if (lane == 0) {
    sim_logits[wave] = s + sb2[0];
    float4 o; o.x = c0 + rb2[0]; o.y = c1 + rb2[1]; o.z = c2 + rb2[2]; o.w = c3 + rb2[3];
    *(float4*)(reg_out + (size_t)wave * 4) = o;
  }
}

// --- fp32 softmax + top-32 candidate superset -------------------------------
__global__ __launch_bounds__(64) void softmax_cand32_kernel(
    const float* __restrict__ logits, float* __restrict__ sim_out,
    int* __restrict__ candn)
{
  int row = blockIdx.x, lane = threadIdx.x;
  float v[4];
#pragma unroll
  for (int i = 0; i < 4; ++i) v[i] = logits[row * 256 + i * 64 + lane];
  float m = fmaxf(fmaxf(v[0], v[1]), fmaxf(v[2], v[3]));
#pragma unroll
  for (int off = 32; off; off >>= 1) m = fmaxf(m, __shfl_xor(m, off));
  float e[4], ssum = 0.f;
#pragma unroll
  for (int i = 0; i < 4; ++i) { e[i] = expf(v[i] - m); ssum += e[i]; }
#pragma unroll
  for (int off = 32; off; off >>= 1) ssum += __shfl_xor(ssum, off);
#pragma unroll
  for (int i = 0; i < 4; ++i)
    sim_out[row * 256 + i * 64 + lane] = e[i] / ssum;
  // top-32 candidate superset by fp32 value (exact order irrelevant)
  for (int it = 0; it < NCAND; ++it) {
    float bv = -3.0e38f; int bi = 0;
#pragma unroll
    for (int i = 0; i < 4; ++i)
      if (v[i] > bv) { bv = v[i]; bi = i * 64 + lane; }
#pragma unroll
    for (int off = 32; off; off >>= 1) {
      float ov = __shfl_xor(bv, off);
      int   oi = __shfl_xor(bi, off);
      if (ov > bv || (ov == bv && oi < bi)) { bv = ov; bi = oi; }
    }
    if (lane == 0) candn[row * NCAND + it] = bi;
    if ((bi & 63) == lane) v[bi >> 6] = -3.4e38f;
  }
}

// --- fp64+EPS top-16 over the 32 candidates (identical semantics to r5) -----
__global__ __launch_bounds__(64) void topk_cand64_kernel(
    const double* __restrict__ clog, const int* __restrict__ candn,
    int* __restrict__ top_idx)
{
  int row = blockIdx.x, lane = threadIdx.x;
  double v = (lane < NCAND) ? clog[row * NCAND + lane] : -1.0e300;
  int    n = (lane < NCAND) ? candn[row * NCAND + lane] : (1 << 29);
  const double EPS = 2.5e-7;
  for (int it = 0; it < TOPN; ++it) {
    double vm = v;
#pragma unroll
    for (int off = 32; off; off >>= 1) vm = fmax(vm, __shfl_xor(vm, off));
    double thr = vm - EPS;
    int bn = (v >= thr) ? n : (1 << 30);
#pragma unroll
    for (int off = 32; off; off >>= 1) {
      int o = __shfl_xor(bn, off);
      if (o < bn) bn = o;
    }
    if (lane == 0) top_idx[row * TOPN + it] = bn;
    if (n == bn) v = -1.0e300;  // n unique within a row
  }
}

__global__ __launch_bounds__(64) void softmax16_kernel(
    const float* __restrict__ logits, float* __restrict__ out)
{
  int row = blockIdx.x, lane = threadIdx.x;
  float v = (lane < TOPN) ? logits[row * TOPN + lane] : -1e30f;
  float m = v;
#pragma unroll
  for (int off = 8; off; off >>= 1) m = fmaxf(m, __shfl_xor(m, off));
  float e = (lane < TOPN) ? expf(v - m) : 0.f;
  float s = e;
#pragma unroll
  for (int off = 8; off; off >>= 1) s += __shfl_xor(s, off);
  if (lane < TOPN) out[row * TOPN + lane] = e / s;
}

__global__ __launch_bounds__(256) void gather_kernel(
    const float* __restrict__ box, const int* __restrict__ top_idx,
    float* __restrict__ bf_top)
{
  int pr = blockIdx.x;            // 0..1023 = (bp, t)
  int bp = pr >> 4, b = bp >> 4;
  int src = b * Nc_ + top_idx[pr];
  const float4* s = (const float4*)(box + (size_t)src * Dc);
  float4* d = (float4*)(bf_top + (size_t)pr * Dc);
  for (int i = threadIdx.x; i < Dc / 4; i += 256) d[i] = s[i];
}

}  // namespace

extern "C" void kernel_launch(void* const* d_in, const int* in_sizes, int n_in,
                              void* d_out, int out_size, void* d_ws, size_t ws_size,
                              hipStream_t stream) {
  const float* box    = (const float*)d_in[0];
  const float* phrase = (const float*)d_in[1];
  const float* ve_w1  = (const float*)d_in[2];
  const float* ve_b1  = (const float*)d_in[3];
  const float* ve_w2  = (const float*)d_in[4];
  const float* ve_b2  = (const float*)d_in[5];
  const float* sim_w1 = (const float*)d_in[6];
  const float* sim_b1 = (const float*)d_in[7];
  const float* sim_w2 = (const float*)d_in[8];
  const float* sim_b2 = (const float*)d_in[9];
  const float* reg_w1 = (const float*)d_in[10];
  const float* reg_b1 = (const float*)d_in[11];
  const float* reg_w2 = (const float*)d_in[12];
  const float* reg_b2 = (const float*)d_in[13];
  const float* vet_w1 = (const float*)d_in[14];
  const float* vet_b1 = (const float*)d_in[15];
  const float* vet_w2 = (const float*)d_in[16];
  const float* vet_b2 = (const float*)d_in[17];
  const float* simt_w1 = (const float*)d_in[18];
  const float* simt_b1 = (const float*)d_in[19];
  const float* simt_w2 = (const float*)d_in[20];
  const float* simt_b2 = (const float*)d_in[21];
  const float* regt_w1 = (const float*)d_in[22];
  const float* regt_b1 = (const float*)d_in[23];
  const float* regt_w2 = (const float*)d_in[24];
  const float* regt_b2 = (const float*)d_in[25];

  float* out = (float*)d_out;
  float* o_sim  = out;                 // [16384]
  float* o_reg  = out + PAIRS1;        // [65536]
  float* o_simt = out + 81920;         // [1024]
  float* o_regt = out + 82944;         // [4096]

  // --- workspace layout (peak 41 MB) ---
  constexpr size_t MB = 1u << 20;
  char* w = (char*)d_ws;
  double* vis64  = (double*)(w + 0 * MB);        // 8MB  [P1-P4]
  // B region 8-16MB: H64 (P1) -> fp32 preps/X (P2-P3) -> stage-2 (P5)
  double* H64    = (double*)(w + 8 * MB);        // 8MB  (P1 only)
  float*  WcVs   = (float*)(w + 8 * MB);         // 1MB
  float*  WcPs   = (float*)(w + 9 * MB);         // 1MB
  float*  WcVPs  = (float*)(w + 10 * MB);        // 1MB
  float*  WcVr   = (float*)(w + 11 * MB);        // 1MB
  float*  WcPr   = (float*)(w + 12 * MB);        // 1MB
  float*  WcVPr  = (float*)(w + 13 * MB);        // 1MB
  float*  Xv32s  = (float*)(w + 14 * MB);        // 1MB
  float*  Xv32r  = (float*)(w + 15 * MB);        // 1MB
  float*  WcVt   = (float*)(w + 8 * MB);         // P5 aliases (B dead)
  float*  WcPt   = (float*)(w + 10 * MB);
  float*  WcVPt  = (float*)(w + 12 * MB);
  float*  Xvt    = (float*)(w + 14 * MB);        // 2MB [1024][512] f32
  double* WcV64  = (double*)(w + 16 * MB);       // 2MB (P2)
  double* WcP64  = (double*)(w + 18 * MB);       // 2MB (P2)
  float*  Xpt    = (float*)(w + 16 * MB);        // P5 aliases (128KB)
  float*  hidnt  = (float*)(w + 17 * MB);        // P5 aliases (2MB)
  double* WcVP64 = (double*)(w + 20 * MB);       // 2MB (P2-P4)
  double* Xv64   = (double*)(w + 22 * MB);       // 2MB (P2-P4)
  // small block @24MB
  double* Xp64    = (double*)(w + 24 * MB);            // 128KB
  double* b1c64   = (double*)(w + 24 * MB + 128 * 1024);
  float*  b1cs    = (float*) (w + 24 * MB + 192 * 1024);
  float*  b1cr    = (float*) (w + 24 * MB + 256 * 1024);
  float*  b1ct    = (float*) (w + 24 * MB + 320 * 1024);
  float*  Xp32s   = (float*) (w + 24 * MB + 384 * 1024); // 64KB
  float*  Xp32r   = (float*) (w + 24 * MB + 448 * 1024); // 64KB
  float*  simlog32= (float*) (w + 24 * MB + 512 * 1024); // 64KB
  int*    candn   = (int*)   (w + 24 * MB + 640 * 1024); // 8KB
  double* clog64  = (double*)(w + 24 * MB + 704 * 1024); // 16KB
  int*    topidx  = (int*)   (w + 24 * MB + 768 * 1024); // 4KB
  float*  simtlog = (float*) (w + 24 * MB + 832 * 1024); // 4KB
  // BIG region 25-41MB
  float*  hid16  = (float*)(w + 25 * MB);        // 16MB [16384][256] (P3)
  double* H2     = (double*)(w + 25 * MB);       // 4MB  (P4, hid16 dead)
  float*  bftop  = (float*)(w + 25 * MB);        // 8MB  (P5, H2 dead)
  float*  H1t    = (float*)(w + 33 * MB);        // 4MB  (P5)
  float*  vist   = (float*)(w + 37 * MB);        // 4MB  (P5)

  // ---- P1: vis64 (fp64, feeds both precision paths) ----
  dgemm64_kernel<float, float, true, false, true><<<dim3(16, 16), 256, 0, stream>>>(
      box, ve_w1, ve_b1, H64, nullptr, 1024, Rc, Dc);
  dgemm64_kernel<double, float, true, false, false><<<dim3(16, 16), 256, 0, stream>>>(
      H64, ve_w2, ve_b2, vis64, nullptr, 1024, Rc, Rc);

  // ---- P2: weight prep + X precomputes ----
  prep_sim64_kernel<<<Rc * HS / 256, 256, 0, stream>>>(
      sim_w1, sim_b1, WcV64, WcP64, WcVP64, b1c64);
  prep_head32_kernel<<<Rc * HS / 256, 256, 0, stream>>>(
      sim_w1, sim_b1, WcVs, WcPs, WcVPs, b1cs);
  prep_head32_kernel<<<Rc * HS / 256, 256, 0, stream>>>(
      reg_w1, reg_b1, WcVr, WcPr, WcVPr, b1cr);
  dgemm64_kernel<double, double, true, false, false><<<dim3(4, 16), 256, 0, stream>>>(
      vis64, WcV64, nullptr, Xv64, nullptr, 1024, HS, Rc);
  dgemm64_kernel<float, double, true, false, false><<<dim3(4, 1), 256, 0, stream>>>(
      phrase, WcP64, nullptr, Xp64, nullptr, BPc, HS, Rc);
  dgemm64_kernel<double, float, false, true, false><<<dim3(4, 16), 256, 0, stream>>>(
      vis64, WcVs, nullptr, nullptr, Xv32s, 1024, HS, Rc);
  sgemm_kernel<64, 64, 32, 4, 4><<<dim3(4, 1), 256, 0, stream>>>(
      phrase, WcPs, nullptr, Xp32s, BPc, HS, Rc, 0);
  dgemm64_kernel<double, float, false, true, false><<<dim3(4, 16), 256, 0, stream>>>(
      vis64, WcVr, nullptr, nullptr, Xv32r, 1024, HS, Rc);
  sgemm_kernel<64, 64, 32, 4, 4><<<dim3(4, 1), 256, 0, stream>>>(
      phrase, WcPr, nullptr, Xp32r, BPc, HS, Rc, 0);

  // ---- P3: fp32 sim head -> o_sim + candidates; fp32 reg head -> o_reg ----
  pair_gemm_kernel<128, 128, 32, 8, 8, 1, HS, double><<<dim3(2, 128), 256, 0, stream>>>(
      vis64, phrase, WcVPs, Xv32s, Xp32s, b1cs, hid16, PAIRS1);
  layer2_sim32_kernel<<<PAIRS1 / 4, 256, 0, stream>>>(
      hid16, sim_w2, sim_b2, simlog32, PAIRS1);
  softmax_cand32_kernel<<<BPc, 64, 0, stream>>>(simlog32, o_sim, candn);
  pair_gemm_kernel<128, 128, 32, 8, 8, 1, HS, double><<<dim3(2, 128), 256, 0, stream>>>(
      vis64, phrase, WcVPr, Xv32r, Xp32r, b1cr, hid16, PAIRS1);
  layer2_reg32_kernel<<<PAIRS1 / 4, 256, 0, stream>>>(
      hid16, reg_w2, reg_b2, o_reg, PAIRS1);

  // ---- P4: fp64 rescore of candidates + EPS top-16 (r5 semantics) ----
  pair64c_kernel<<<dim3(4, CPAIRS / 64), 256, 0, stream>>>(
      vis64, phrase, WcVP64, Xv64, Xp64, b1c64, candn, H2);
  layer2_sim64_kernel<<<CPAIRS / 4, 256, 0, stream>>>(
      H2, sim_w2, sim_b2, clog64, CPAIRS);
  topk_cand64_kernel<<<BPc, 64, 0, stream>>>(clog64, candn, topidx);

  // ---- P5: stage 2 (fp32, unchanged from r5) ----
  gather_kernel<<<PAIRS2, 256, 0, stream>>>(box, topidx, bftop);
  prep_t_kernel<<<Rc * HO / 256, 256, 0, stream>>>(
      simt_w1, regt_w1, simt_b1, regt_b1, WcVt, WcPt, WcVPt, b1ct);
  sgemm_kernel<128, 64, 32, 8, 4><<<dim3(16, 8), 256, 0, stream>>>(
      bftop, vet_w1, vet_b1, H1t, 1024, Rc, Dc, 1);
  sgemm_kernel<128, 64, 32, 8, 4><<<dim3(16, 8), 256, 0, stream>>>(
      H1t, vet_w2, vet_b2, vist, 1024, Rc, Rc, 0);
  sgemm_kernel<64, 64, 32, 4, 4><<<dim3(8, 16), 256, 0, stream>>>(
      vist, WcVt, nullptr, Xvt, 1024, HO, Rc, 0);
  sgemm_kernel<64, 64, 32, 4, 4><<<dim3(8, 1), 256, 0, stream>>>(
      phrase, WcPt, nullptr, Xpt, BPc, HO, Rc, 0);
  pair_gemm_kernel<64, 64, 32, 4, 4, 2, HO, float><<<dim3(8, 16), 256, 0, stream>>>(
      vist, phrase, WcVPt, Xvt, Xpt, b1ct, hidnt, PAIRS2);
  layer2_t_kernel<<<PAIRS2 / 4, 256, 0, stream>>>(
      hidnt, simt_w2, simt_b2, regt_w2, regt_b2, simtlog, o_regt, PAIRS2);
  softmax16_kernel<<<BPc, 64, 0, stream>>>(simtlog, o_simt);
}

// Round 7
// 1571.931 us; speedup vs baseline: 1.3933x; 1.3933x over previous
//
#include <hip/hip_runtime.h>
#include <hip/hip_bf16.h>

// DetProposalVGHead on MI355X.
// fused = [v, p, v*p, v-p]  =>  fused@W1 = v@(Wa+Wd) + p@(Wb-Wd) + (v*p)@Wc
//
// Validated semantics (r5/r6 GREEN): top-k = exact-arithmetic ordering with
// EPS=2.5e-7 tie-window resolved to LOWEST index; fp64 chain only needs
// ~1e-9 accuracy (NOT bit-exactness), so fp64 GEMMs may be freely re-tiled.
// Round-7: occupancy-fixed 32x64 fp64 GEMMs (512 blocks for the big MLP),
// single combined 512-wide fp32 sim|reg pair-GEMM, pure-fp32 vis for the
// value/prescreen path, merged preps, fewer launches.

namespace {

constexpr int Nc_   = 256;    // boxes
constexpr int Dc    = 2048;
constexpr int Rc    = 1024;
constexpr int TOPN  = 16;
constexpr int NCAND = 32;     // fp32 prescreen candidates per row
constexpr int HS    = 256;    // per-head hidden width
constexpr int HO    = 512;    // combined (sim|reg) hidden width
constexpr int BPc   = 64;     // B*P
constexpr int PAIRS1 = 16384; // B*P*N
constexpr int PAIRS2 = 1024;  // B*P*topN
constexpr int CPAIRS = BPc * NCAND; // 2048

__device__ __forceinline__ float  leaky01f(float x)  { return x > 0.f ? x : 0.01f * x; }
__device__ __forceinline__ double leaky01d(double x) { return x > 0.0 ? x : 0.01  * x; }

// ---------------------------------------------------------------------------
// fp64 GEMM v2: C64 = act(A @ W + bias). BM=32, BN=64, BK=16, 256 thr,
// TM=2, TN=4. Grid (N/64, M/32) -> 512 blocks for 1024x1024 (2/CU).
// Accuracy-only (any accumulation order OK; error ~1e-13).
// ---------------------------------------------------------------------------
template <typename TA, typename TW, bool LEAKY>
__global__ __launch_bounds__(256) void dg64_kernel(
    const TA* __restrict__ A, const TW* __restrict__ W, const float* __restrict__ bias,
    double* __restrict__ C64, int M, int N, int K)
{
  __shared__ double As[16][33];
  __shared__ double Bs[16][66];
  const int t = threadIdx.x, tx = t & 15, ty = t >> 4;
  const int row0 = blockIdx.y * 32, col0 = blockIdx.x * 64;
  double acc[2][4] = {};

  const int mm = t >> 3, kqa = (t & 7) * 2;   // A-stage: 32 rows x 16 k
  const int kkb = t >> 4, nqb = (t & 15) * 4; // B-stage: 16 k x 64 n

  for (int k0 = 0; k0 < K; k0 += 16) {
    {
      const TA* src = A + (size_t)(row0 + mm) * K + k0 + kqa;
      double v0, v1;
      if constexpr (sizeof(TA) == 4) {
        float2 f = *(const float2*)src; v0 = f.x; v1 = f.y;
      } else {
        double2 d = *(const double2*)src; v0 = d.x; v1 = d.y;
      }
      As[kqa][mm] = v0; As[kqa + 1][mm] = v1;
    }
    {
      const TW* src = W + (size_t)(k0 + kkb) * N + col0 + nqb;
      if constexpr (sizeof(TW) == 4) {
        float4 f = *(const float4*)src;
        Bs[kkb][nqb] = f.x; Bs[kkb][nqb + 1] = f.y;
        Bs[kkb][nqb + 2] = f.z; Bs[kkb][nqb + 3] = f.w;
      } else {
        double2 a = *(const double2*)src, b = *(const double2*)(src + 2);
        Bs[kkb][nqb] = a.x; Bs[kkb][nqb + 1] = a.y;
        Bs[kkb][nqb + 2] = b.x; Bs[kkb][nqb + 3] = b.y;
      }
    }
    __syncthreads();
#pragma unroll
    for (int kk = 0; kk < 16; ++kk) {
      double a[2], b[4];
#pragma unroll
      for (int i = 0; i < 2; ++i) a[i] = As[kk][ty * 2 + i];
#pragma unroll
      for (int j = 0; j < 4; ++j) b[j] = Bs[kk][tx + 16 * j];
#pragma unroll
      for (int i = 0; i < 2; ++i)
#pragma unroll
        for (int j = 0; j < 4; ++j) acc[i][j] = fma(a[i], b[j], acc[i][j]);
    }
    __syncthreads();
  }

#pragma unroll
  for (int i = 0; i < 2; ++i) {
    int r = row0 + ty * 2 + i;
#pragma unroll
    for (int j = 0; j < 4; ++j) {
      int c = col0 + tx + 16 * j;
      double v = acc[i][j];
      if (bias) v += (double)bias[c];
      if constexpr (LEAKY) v = leaky01d(v);
      C64[(size_t)r * N + c] = v;
    }
  }
}

// ---------------------------------------------------------------------------
// fp64 candidate pair GEMM v2 (32-row tiles): for m in [0,CPAIRS):
// bp=m>>5, n=candn[m], vr=(bp>>4)*256+n, pr=bp.
// H[m,c] = leaky((vis64[vr]*phr[pr])@W + Xv[vr] + Xp[pr] + b1).  N=HS=256.
// Grid (4, CPAIRS/32=64) = 256 blocks.
// ---------------------------------------------------------------------------
__global__ __launch_bounds__(256) void pair64c_kernel(
    const double* __restrict__ vis, const float* __restrict__ phr,
    const double* __restrict__ W, const double* __restrict__ Xv,
    const double* __restrict__ Xp, const double* __restrict__ b1,
    const int* __restrict__ candn, double* __restrict__ H)
{
  __shared__ double As[16][33];
  __shared__ double Bs[16][66];
  const int t = threadIdx.x, tx = t & 15, ty = t >> 4;
  const int row0 = blockIdx.y * 32, col0 = blockIdx.x * 64;
  double acc[2][4] = {};

  const int mm = t >> 3, kqa = (t & 7) * 2;
  const int kkb = t >> 4, nqb = (t & 15) * 4;
  const int ms = row0 + mm, bps = ms >> 5;
  const int vrs = ((bps >> 4) << 8) | candn[ms], prs = bps;

  for (int k0 = 0; k0 < Rc; k0 += 16) {
    {
      double2 v = *(const double2*)(vis + (size_t)vrs * Rc + k0 + kqa);
      float2  p = *(const float2*)(phr + (size_t)prs * Rc + k0 + kqa);
      As[kqa][mm]     = v.x * (double)p.x;
      As[kqa + 1][mm] = v.y * (double)p.y;
    }
    {
      const double* src = W + (size_t)(k0 + kkb) * HS + col0 + nqb;
      double2 a = *(const double2*)src, b = *(const double2*)(src + 2);
      Bs[kkb][nqb] = a.x; Bs[kkb][nqb + 1] = a.y;
      Bs[kkb][nqb + 2] = b.x; Bs[kkb][nqb + 3] = b.y;
    }
    __syncthreads();
#pragma unroll
    for (int kk = 0; kk < 16; ++kk) {
      double a[2], b[4];
#pragma unroll
      for (int i = 0; i < 2; ++i) a[i] = As[kk][ty * 2 + i];
#pragma unroll
      for (int j = 0; j < 4; ++j) b[j] = Bs[kk][tx + 16 * j];
#pragma unroll
      for (int i = 0; i < 2; ++i)
#pragma unroll
        for (int j = 0; j < 4; ++j) acc[i][j] = fma(a[i], b[j], acc[i][j]);
    }
    __syncthreads();
  }

#pragma unroll
  for (int i = 0; i < 2; ++i) {
    int r = row0 + ty * 2 + i, bp = r >> 5;
    int vr = ((bp >> 4) << 8) | candn[r], pr = bp;
#pragma unroll
    for (int j = 0; j < 4; ++j) {
      int c = col0 + tx + 16 * j;
      double v = acc[i][j] + Xv[(size_t)vr * HS + c] + Xp[(size_t)pr * HS + c] + b1[c];
      H[(size_t)r * HS + c] = leaky01d(v);
    }
  }
}

// ---------------------------------------------------------------------------
// fp32 tiled GEMM: C = act(A@W + bias).
// ---------------------------------------------------------------------------
template <int BM, int BN, int BK, int TM, int TN>
__global__ __launch_bounds__(256) void sgemm_kernel(
    const float* __restrict__ A, const float* __restrict__ W,
    const float* __restrict__ bias, float* __restrict__ C,
    int M, int Nc, int K, int leaky)
{
  constexpr int THREADS = (BM / TM) * (BN / TN);
  static_assert(THREADS == 256, "block must be 256");
  __shared__ float As[BK][BM];
  __shared__ float Bs[BK][BN];

  const int t = threadIdx.x;
  const int tx = t % (BN / TN), ty = t / (BN / TN);
  const int row0 = blockIdx.y * BM, col0 = blockIdx.x * BN;
  float acc[TM][TN] = {};

  for (int k0 = 0; k0 < K; k0 += BK) {
    constexpr int AV = BM * BK / 4 / THREADS;
#pragma unroll
    for (int p_ = 0; p_ < AV; ++p_) {
      int f = p_ * THREADS + t;
      int mm = f / (BK / 4), kq = (f % (BK / 4)) * 4;
      float4 a4 = *(const float4*)(A + (size_t)(row0 + mm) * K + k0 + kq);
      As[kq + 0][mm] = a4.x; As[kq + 1][mm] = a4.y;
      As[kq + 2][mm] = a4.z; As[kq + 3][mm] = a4.w;
    }
    constexpr int BV = BK * BN / 4 / THREADS;
#pragma unroll
    for (int p_ = 0; p_ < BV; ++p_) {
      int f = p_ * THREADS + t;
      int nq = (f % (BN / 4)) * 4, kk = f / (BN / 4);
      *(float4*)&Bs[kk][nq] = *(const float4*)(W + (size_t)(k0 + kk) * Nc + col0 + nq);
    }
    __syncthreads();
#pragma unroll
    for (int kk = 0; kk < BK; ++kk) {
      float a[TM], bb[TN];
#pragma unroll
      for (int i = 0; i < TM; i += 4) {
        float4 v = *(const float4*)&As[kk][ty * TM + i];
        a[i] = v.x; a[i + 1] = v.y; a[i + 2] = v.z; a[i + 3] = v.w;
      }
#pragma unroll
      for (int j = 0; j < TN; j += 4) {
        float4 v = *(const float4*)&Bs[kk][tx * TN + j];
        bb[j] = v.x; bb[j + 1] = v.y; bb[j + 2] = v.z; bb[j + 3] = v.w;
      }
#pragma unroll
      for (int i = 0; i < TM; ++i)
#pragma unroll
        for (int j = 0; j < TN; ++j) acc[i][j] = fmaf(a[i], bb[j], acc[i][j]);
    }
    __syncthreads();
  }

#pragma unroll
  for (int i = 0; i < TM; ++i) {
    int r = row0 + ty * TM + i;
#pragma unroll
    for (int j = 0; j < TN; j += 4) {
      int c = col0 + tx * TN + j;
      float4 o;
      o.x = acc[i][j]; o.y = acc[i][j + 1]; o.z = acc[i][j + 2]; o.w = acc[i][j + 3];
      if (bias) {
        float4 bv = *(const float4*)(bias + c);
        o.x += bv.x; o.y += bv.y; o.z += bv.z; o.w += bv.w;
      }
      if (leaky) { o.x = leaky01f(o.x); o.y = leaky01f(o.y); o.z = leaky01f(o.z); o.w = leaky01f(o.w); }
      *(float4*)(C + (size_t)r * Nc + c) = o;
    }
  }
}

// ---------------------------------------------------------------------------
// fp32 pair GEMM (combined sim|reg). vis is float.
// STAGE 1: pair = bp*256 + n (vr=(bp>>4)*256+n, pr=bp). STAGE 2: vr=m, pr=m>>4.
// ---------------------------------------------------------------------------
template <int BM, int BN, int BK, int TM, int TN, int STAGE, int NCOL>
__global__ __launch_bounds__(256) void pair_gemm_kernel(
    const float* __restrict__ vis, const float* __restrict__ phr,
    const float* __restrict__ Wvp, const float* __restrict__ Xv,
    const float* __restrict__ Xp, const float* __restrict__ b1c,
    float* __restrict__ Hout, int M)
{
  constexpr int THREADS = (BM / TM) * (BN / TN);
  static_assert(THREADS == 256, "block must be 256");
  __shared__ float As[BK][BM];
  __shared__ float Bs[BK][BN];

  const int t = threadIdx.x;
  const int tx = t % (BN / TN), ty = t / (BN / TN);
  const int row0 = blockIdx.y * BM, col0 = blockIdx.x * BN;
  float acc[TM][TN] = {};

  for (int k0 = 0; k0 < Rc; k0 += BK) {
    constexpr int AV = BM * BK / 4 / THREADS;
#pragma unroll
    for (int p_ = 0; p_ < AV; ++p_) {
      int f = p_ * THREADS + t;
      int mm = f / (BK / 4), kq = (f % (BK / 4)) * 4;
      int m = row0 + mm;
      int vr, pr;
      if (STAGE == 1) { int bp = m >> 8; pr = bp; vr = ((bp >> 4) << 8) | (m & 255); }
      else            { vr = m; pr = m >> 4; }
      float4 v4 = *(const float4*)(vis + (size_t)vr * Rc + k0 + kq);
      float4 p4 = *(const float4*)(phr + (size_t)pr * Rc + k0 + kq);
      As[kq + 0][mm] = v4.x * p4.x; As[kq + 1][mm] = v4.y * p4.y;
      As[kq + 2][mm] = v4.z * p4.z; As[kq + 3][mm] = v4.w * p4.w;
    }
    constexpr int BV = BK * BN / 4 / THREADS;
#pragma unroll
    for (int p_ = 0; p_ < BV; ++p_) {
      int f = p_ * THREADS + t;
      int nq = (f % (BN / 4)) * 4, kk = f / (BN / 4);
      *(float4*)&Bs[kk][nq] = *(const float4*)(Wvp + (size_t)(k0 + kk) * NCOL + col0 + nq);
    }
    __syncthreads();
#pragma unroll
    for (int kk = 0; kk < BK; ++kk) {
      float a[TM], bb[TN];
#pragma unroll
      for (int i = 0; i < TM; i += 4) {
        float4 v = *(const float4*)&As[kk][ty * TM + i];
        a[i] = v.x; a[i + 1] = v.y; a[i + 2] = v.z; a[i + 3] = v.w;
      }
#pragma unroll
      for (int j = 0; j < TN; j += 4) {
        float4 v = *(const float4*)&Bs[kk][tx * TN + j];
        bb[j] = v.x; bb[j + 1] = v.y; bb[j + 2] = v.z; bb[j + 3] = v.w;
      }
#pragma unroll
      for (int i = 0; i < TM; ++i)
#pragma unroll
        for (int j = 0; j < TN; ++j) acc[i][j] = fmaf(a[i], bb[j], acc[i][j]);
    }
    __syncthreads();
  }

#pragma unroll
  for (int i = 0; i < TM; ++i) {
    int r = row0 + ty * TM + i;
    int vr, pr;
    if (STAGE == 1) { int bp = r >> 8; pr = bp; vr = ((bp >> 4) << 8) | (r & 255); }
    else            { vr = r; pr = r >> 4; }
#pragma unroll
    for (int j = 0; j < TN; j += 4) {
      int c = col0 + tx * TN + j;
      float4 xv = *(const float4*)(Xv + (size_t)vr * NCOL + c);
      float4 xp = *(const float4*)(Xp + (size_t)pr * NCOL + c);
      float4 bv = *(const float4*)(b1c + c);
      float4 o;
      o.x = leaky01f(acc[i][j]     + xv.x + xp.x + bv.x);
      o.y = leaky01f(acc[i][j + 1] + xv.y + xp.y + bv.y);
      o.z = leaky01f(acc[i][j + 2] + xv.z + xp.z + bv.z);
      o.w = leaky01f(acc[i][j + 3] + xv.w + xp.w + bv.w);
      *(float4*)(Hout + (size_t)r * NCOL + c) = o;
    }
  }
}

// --- merged weight prep: fp64 sim head + stage-1 combined fp32 --------------
__global__ __launch_bounds__(256) void prep_stage1_kernel(
    const float* __restrict__ sim_w1, const float* __restrict__ sim_b1,
    const float* __restrict__ reg_w1, const float* __restrict__ reg_b1,
    double* __restrict__ WV64, double* __restrict__ WP64, double* __restrict__ WVP64,
    double* __restrict__ b64,
    float* __restrict__ W1V, float* __restrict__ W1P, float* __restrict__ W1VP,
    float* __restrict__ b1)
{
  int bid = blockIdx.x;
  if (bid < 1024) {                         // fp64 sim head: Rc*HS items
    int idx = bid * 256 + threadIdx.x;
    int r = idx >> 8, c = idx & 255;
    double wa = (double)sim_w1[(size_t)(0 * Rc + r) * 256 + c];
    double wb = (double)sim_w1[(size_t)(1 * Rc + r) * 256 + c];
    double wc = (double)sim_w1[(size_t)(2 * Rc + r) * 256 + c];
    double wd = (double)sim_w1[(size_t)(3 * Rc + r) * 256 + c];
    WV64[idx] = wa + wd; WP64[idx] = wb - wd; WVP64[idx] = wc;
    if (r == 0) b64[c] = (double)sim_b1[c];
  } else {                                  // combined fp32: Rc*HO items
    int idx = (bid - 1024) * 256 + threadIdx.x;
    int r = idx >> 9, j = idx & (HO - 1);
    const float* w1 = (j < 256) ? sim_w1 : reg_w1;
    int c = j & 255;
    float wa = w1[(size_t)(0 * Rc + r) * 256 + c];
    float wb = w1[(size_t)(1 * Rc + r) * 256 + c];
    float wc = w1[(size_t)(2 * Rc + r) * 256 + c];
    float wd = w1[(size_t)(3 * Rc + r) * 256 + c];
    W1V[idx] = wa + wd; W1P[idx] = wb - wd; W1VP[idx] = wc;
    if (r == 0) b1[j] = (j < 256) ? sim_b1[c] : reg_b1[c];
  }
}

__global__ __launch_bounds__(256) void prep_t_kernel(
    const float* __restrict__ simw1, const float* __restrict__ regw1,
    const float* __restrict__ simb1, const float* __restrict__ regb1,
    float* __restrict__ Wv, float* __restrict__ Wp, float* __restrict__ Wvp,
    float* __restrict__ b1c)
{
  int idx = blockIdx.x * 256 + threadIdx.x;  // Rc*HO
  int r = idx >> 9, j = idx & (HO - 1);
  const float* w1 = (j < 256) ? simw1 : regw1;
  int c = j & 255;
  float wa = w1[(size_t)(0 * Rc + r) * 256 + c];
  float wb = w1[(size_t)(1 * Rc + r) * 256 + c];
  float wc = w1[(size_t)(2 * Rc + r) * 256 + c];
  float wd = w1[(size_t)(3 * Rc + r) * 256 + c];
  Wv[idx] = wa + wd; Wp[idx] = wb - wd; Wvp[idx] = wc;
  if (r == 0) b1c[j] = (j < 256) ? simb1[c] : regb1[c];
}

// --- second layers ---------------------------------------------------------
// combined (hidden stride HO=512): sim logit + reg[4] per pair, one wave each
__global__ __launch_bounds__(256) void layer2_t_kernel(
    const float* __restrict__ hidden,
    const float* __restrict__ sw2, const float* __restrict__ sb2,
    const float* __restrict__ rw2, const float* __restrict__ rb2,
    float* __restrict__ sim_logits, float* __restrict__ reg_out, int M)
{
  int wave = (blockIdx.x * blockDim.x + threadIdx.x) >> 6, lane = threadIdx.x & 63;
  if (wave >= M) return;
  const float* h = hidden + (size_t)wave * HO;
  float4 hs = *(const float4*)(h + lane * 4);
  float4 hr = *(const float4*)(h + 256 + lane * 4);
  float4 ws = *(const float4*)(sw2 + lane * 4);
  float s = hs.x * ws.x + hs.y * ws.y + hs.z * ws.z + hs.w * ws.w;
  float4 r0 = *(const float4*)(rw2 + (size_t)(lane * 4 + 0) * 4);
  float4 r1 = *(const float4*)(rw2 + (size_t)(lane * 4 + 1) * 4);
  float4 r2 = *(const float4*)(rw2 + (size_t)(lane * 4 + 2) * 4);
  float4 r3 = *(const float4*)(rw2 + (size_t)(lane * 4 + 3) * 4);
  float c0 = hr.x * r0.x + hr.y * r1.x + hr.z * r2.x + hr.w * r3.x;
  float c1 = hr.x * r0.y + hr.y * r1.y + hr.z * r2.y + hr.w * r3.y;
  float c2 = hr.x * r0.z + hr.y * r1.z + hr.z * r2.z + hr.w * r3.z;
  float c3 = hr.x * r0.w + hr.y * r1.w + hr.z * r2.w + hr.w * r3.w;
#pragma unroll
  for (int off = 32; off; off >>= 1) {
    s  += __shfl_xor(s, off);
    c0 += __shfl_xor(c0, off); c1 += __shfl_xor(c1, off);
    c2 += __shfl_xor(c2, off); c3 += __shfl_xor(c3, off);
  }
  if (lane == 0) {
    sim_logits[wave] = s + sb2[0];
    float4 o; o.x = c0 + rb2[0]; o.y = c1 + rb2[1]; o.z = c2 + rb2[2]; o.w = c3 + rb2[3];
    *(float4*)(reg_out + (size_t)wave * 4) = o;
  }
}

__global__ __launch_bounds__(256) void layer2_sim64_kernel(
    const double* __restrict__ h, const float* __restrict__ sw2,
    const float* __restrict__ sb2, double* __restrict__ out, int M)
{
  int wave = (blockIdx.x * blockDim.x + threadIdx.x) >> 6, lane = threadIdx.x & 63;
  if (wave >= M) return;
  const double* hr = h + (size_t)wave * HS + lane * 4;
  double2 h0 = *(const double2*)hr, h1 = *(const double2*)(hr + 2);
  float4 w = *(const float4*)(sw2 + lane * 4);
  double s = h0.x * (double)w.x + h0.y * (double)w.y + h1.x * (double)w.z + h1.y * (double)w.w;
#pragma unroll
  for (int off = 32; off; off >>= 1) s += __shfl_xor(s, off);
  if (lane == 0) out[wave] = s + (double)sb2[0];
}

// --- fp32 softmax + top-32 candidate superset -------------------------------
__global__ __launch_bounds__(64) void softmax_cand32_kernel(
    const float* __restrict__ logits, float* __restrict__ sim_out,
    int* __restrict__ candn)
{
  int row = blockIdx.x, lane = threadIdx.x;
  float v[4];
#pragma unroll
  for (int i = 0; i < 4; ++i) v[i] = logits[row * 256 + i * 64 + lane];
  float m = fmaxf(fmaxf(v[0], v[1]), fmaxf(v[2], v[3]));
#pragma unroll
  for (int off = 32; off; off >>= 1) m = fmaxf(m, __shfl_xor(m, off));
  float e[4], ssum = 0.f;
#pragma unroll
  for (int i = 0; i < 4; ++i) { e[i] = expf(v[i] - m); ssum += e[i]; }
#pragma unroll
  for (int off = 32; off; off >>= 1) ssum += __shfl_xor(ssum, off);
#pragma unroll
  for (int i = 0; i < 4; ++i)
    sim_out[row * 256 + i * 64 + lane] = e[i] / ssum;
  for (int it = 0; it < NCAND; ++it) {
    float bv = -3.0e38f; int bi = 0;
#pragma unroll
    for (int i = 0; i < 4; ++i)
      if (v[i] > bv) { bv = v[i]; bi = i * 64 + lane; }
#pragma unroll
    for (int off = 32; off; off >>= 1) {
      float ov = __shfl_xor(bv, off);
      int   oi = __shfl_xor(bi, off);
      if (ov > bv || (ov == bv && oi < bi)) { bv = ov; bi = oi; }
    }
    if (lane == 0) candn[row * NCAND + it] = bi;
    if ((bi & 63) == lane) v[bi >> 6] = -3.4e38f;
  }
}

// --- fp64+EPS top-16 over 32 candidates (validated r5/r6 semantics) ---------
__global__ __launch_bounds__(64) void topk_cand64_kernel(
    const double* __restrict__ clog, const int* __restrict__ candn,
    int* __restrict__ top_idx)
{
  int row = blockIdx.x, lane = threadIdx.x;
  double v = (lane < NCAND) ? clog[row * NCAND + lane] : -1.0e300;
  int    n = (lane < NCAND) ? candn[row * NCAND + lane] : (1 << 29);
  const double EPS = 2.5e-7;
  for (int it = 0; it < TOPN; ++it) {
    double vm = v;
#pragma unroll
    for (int off = 32; off; off >>= 1) vm = fmax(vm, __shfl_xor(vm, off));
    double thr = vm - EPS;
    int bn = (v >= thr) ? n : (1 << 30);
#pragma unroll
    for (int off = 32; off; off >>= 1) {
      int o = __shfl_xor(bn, off);
      if (o < bn) bn = o;
    }
    if (lane == 0) top_idx[row * TOPN + it] = bn;
    if (n == bn) v = -1.0e300;
  }
}

__global__ __launch_bounds__(64) void softmax16_kernel(
    const float* __restrict__ logits, float* __restrict__ out)
{
  int row = blockIdx.x, lane = threadIdx.x;
  float v = (lane < TOPN) ? logits[row * TOPN + lane] : -1e30f;
  float m = v;
#pragma unroll
  for (int off = 8; off; off >>= 1) m = fmaxf(m, __shfl_xor(m, off));
  float e = (lane < TOPN) ? expf(v - m) : 0.f;
  float s = e;
#pragma unroll
  for (int off = 8; off; off >>= 1) s += __shfl_xor(s, off);
  if (lane < TOPN) out[row * TOPN + lane] = e / s;
}

__global__ __launch_bounds__(256) void gather_kernel(
    const float* __restrict__ box, const int* __restrict__ top_idx,
    float* __restrict__ bf_top)
{
  int pr = blockIdx.x;
  int bp = pr >> 4, b = bp >> 4;
  int src = b * Nc_ + top_idx[pr];
  const float4* s = (const float4*)(box + (size_t)src * Dc);
  float4* d = (float4*)(bf_top + (size_t)pr * Dc);
  for (int i = threadIdx.x; i < Dc / 4; i += 256) d[i] = s[i];
}

}  // namespace

extern "C" void kernel_launch(void* const* d_in, const int* in_sizes, int n_in,
                              void* d_out, int out_size, void* d_ws, size_t ws_size,
                              hipStream_t stream) {
  const float* box    = (const float*)d_in[0];
  const float* phrase = (const float*)d_in[1];
  const float* ve_w1  = (const float*)d_in[2];
  const float* ve_b1  = (const float*)d_in[3];
  const float* ve_w2  = (const float*)d_in[4];
  const float* ve_b2  = (const float*)d_in[5];
  const float* sim_w1 = (const float*)d_in[6];
  const float* sim_b1 = (const float*)d_in[7];
  const float* sim_w2 = (const float*)d_in[8];
  const float* sim_b2 = (const float*)d_in[9];
  const float* reg_w1 = (const float*)d_in[10];
  const float* reg_b1 = (const float*)d_in[11];
  const float* reg_w2 = (const float*)d_in[12];
  const float* reg_b2 = (const float*)d_in[13];
  const float* vet_w1 = (const float*)d_in[14];
  const float* vet_b1 = (const float*)d_in[15];
  const float* vet_w2 = (const float*)d_in[16];
  const float* vet_b2 = (const float*)d_in[17];
  const float* simt_w1 = (const float*)d_in[18];
  const float* simt_b1 = (const float*)d_in[19];
  const float* simt_w2 = (const float*)d_in[20];
  const float* simt_b2 = (const float*)d_in[21];
  const float* regt_w1 = (const float*)d_in[22];
  const float* regt_b1 = (const float*)d_in[23];
  const float* regt_w2 = (const float*)d_in[24];
  const float* regt_b2 = (const float*)d_in[25];

  float* out = (float*)d_out;
  float* o_sim  = out;                 // [16384]
  float* o_reg  = out + PAIRS1;        // [65536]
  float* o_simt = out + 81920;         // [1024]
  float* o_regt = out + 82944;         // [4096]

  // --- workspace layout (peak 52.5 MB; proven budget >= 56.7 MB) ---
  constexpr size_t MB = 1u << 20;
  char* w = (char*)d_ws;
  double* WcV64  = (double*)(w + 0 * MB);   // 2MB
  double* WcP64  = (double*)(w + 2 * MB);   // 2MB
  double* WcVP64 = (double*)(w + 4 * MB);   // 2MB
  float*  Wc1V   = (float*)(w + 6 * MB);    // 2MB [1024][512]
  float*  Wc1P   = (float*)(w + 8 * MB);    // 2MB
  float*  Wc1VP  = (float*)(w + 10 * MB);   // 2MB
  // small block @12MB
  char* sm = w + 12 * MB;
  double* b1c64    = (double*)(sm + 0);
  float*  b1c1     = (float*) (sm + 4096);
  float*  b1ct     = (float*) (sm + 8192);
  int*    candn    = (int*)   (sm + 12288);
  double* clog64   = (double*)(sm + 24576);
  int*    topidx   = (int*)   (sm + 40960);
  float*  simtlog  = (float*) (sm + 45056);
  float*  simlog32 = (float*) (sm + 65536);   // 64KB
  float*  Xp32     = (float*) (sm + 131072);  // 128KB [64][512]
  double* Xp64     = (double*)(sm + 262144);  // 128KB [64][256]
  float*  Xpt      = (float*) (sm + 393216);  // 128KB [64][512]
  // region A @12.5MB (8MB)
  float*  H1_32 = (float*)(w + 12 * MB + 524288);        // 4MB (P1, then dead)
  float*  Xv32  = (float*)(w + 12 * MB + 524288);        // 2MB aliases H1_32 (dead)
  float*  vis32 = (float*)(w + 16 * MB + 524288);        // 4MB
  double* vis64 = (double*)(w + 12 * MB + 524288);       // 8MB (P2; fp32 temps dead)
  // BIG region @20.5MB (32MB)
  char* big = w + 20 * MB + 524288;
  float*  hid1  = (float*)(big);                 // 32MB (P1)
  double* H64   = (double*)(big);                // 8MB  (P2)
  double* Xv64  = (double*)(big + 8 * MB);       // 2MB  (P2)
  double* H2    = (double*)(big + 10 * MB);      // 4MB  (P2)
  float*  bftop = (float*)(big);                 // 8MB  (P3)
  float*  H1t   = (float*)(big + 8 * MB);        // 4MB  (P3)
  float*  vist  = (float*)(big + 12 * MB);       // 4MB  (P3)
  float*  Xvt   = (float*)(big + 16 * MB);       // 2MB  (P3)
  float*  hidnt = (float*)(big + 18 * MB);       // 2MB  (P3)
  float*  WcVt  = (float*)(big + 20 * MB);       // 2MB  (P3)
  float*  WcPt  = (float*)(big + 22 * MB);       // 2MB  (P3)
  float*  WcVPt = (float*)(big + 24 * MB);       // 2MB  (P3)

  // ---- P1: fp32 value path (o_sim, o_reg) + candidate prescreen ----
  prep_stage1_kernel<<<3072, 256, 0, stream>>>(
      sim_w1, sim_b1, reg_w1, reg_b1,
      WcV64, WcP64, WcVP64, b1c64, Wc1V, Wc1P, Wc1VP, b1c1);
  sgemm_kernel<64, 64, 32, 4, 4><<<dim3(16, 16), 256, 0, stream>>>(
      box, ve_w1, ve_b1, H1_32, 1024, Rc, Dc, 1);
  sgemm_kernel<64, 64, 32, 4, 4><<<dim3(16, 16), 256, 0, stream>>>(
      H1_32, ve_w2, ve_b2, vis32, 1024, Rc, Rc, 0);
  sgemm_kernel<64, 64, 32, 4, 4><<<dim3(8, 16), 256, 0, stream>>>(
      vis32, Wc1V, nullptr, Xv32, 1024, HO, Rc, 0);
  sgemm_kernel<64, 64, 32, 4, 4><<<dim3(8, 1), 256, 0, stream>>>(
      phrase, Wc1P, nullptr, Xp32, BPc, HO, Rc, 0);
  pair_gemm_kernel<128, 128, 32, 8, 8, 1, HO><<<dim3(4, 128), 256, 0, stream>>>(
      vis32, phrase, Wc1VP, Xv32, Xp32, b1c1, hid1, PAIRS1);
  layer2_t_kernel<<<PAIRS1 / 4, 256, 0, stream>>>(
      hid1, sim_w2, sim_b2, reg_w2, reg_b2, simlog32, o_reg, PAIRS1);
  softmax_cand32_kernel<<<BPc, 64, 0, stream>>>(simlog32, o_sim, candn);

  // ---- P2: fp64 ranking chain on candidates (validated EPS semantics) ----
  dg64_kernel<float, float, true><<<dim3(16, 32), 256, 0, stream>>>(
      box, ve_w1, ve_b1, H64, 1024, Rc, Dc);
  dg64_kernel<double, float, false><<<dim3(16, 32), 256, 0, stream>>>(
      H64, ve_w2, ve_b2, vis64, 1024, Rc, Rc);
  dg64_kernel<double, double, false><<<dim3(4, 32), 256, 0, stream>>>(
      vis64, WcV64, nullptr, Xv64, 1024, HS, Rc);
  dg64_kernel<float, double, false><<<dim3(4, 2), 256, 0, stream>>>(
      phrase, WcP64, nullptr, Xp64, BPc, HS, Rc);
  pair64c_kernel<<<dim3(4, CPAIRS / 32), 256, 0, stream>>>(
      vis64, phrase, WcVP64, Xv64, Xp64, b1c64, candn, H2);
  layer2_sim64_kernel<<<CPAIRS / 4, 256, 0, stream>>>(
      H2, sim_w2, sim_b2, clog64, CPAIRS);
  topk_cand64_kernel<<<BPc, 64, 0, stream>>>(clog64, candn, topidx);

  // ---- P3: stage 2 (fp32) ----
  prep_t_kernel<<<Rc * HO / 256, 256, 0, stream>>>(
      simt_w1, regt_w1, simt_b1, regt_b1, WcVt, WcPt, WcVPt, b1ct);
  gather_kernel<<<PAIRS2, 256, 0, stream>>>(box, topidx, bftop);
  sgemm_kernel<64, 64, 32, 4, 4><<<dim3(16, 16), 256, 0, stream>>>(
      bftop, vet_w1, vet_b1, H1t, 1024, Rc, Dc, 1);
  sgemm_kernel<64, 64, 32, 4, 4><<<dim3(16, 16), 256, 0, stream>>>(
      H1t, vet_w2, vet_b2, vist, 1024, Rc, Rc, 0);
  sgemm_kernel<64, 64, 32, 4, 4><<<dim3(8, 16), 256, 0, stream>>>(
      vist, WcVt, nullptr, Xvt, 1024, HO, Rc, 0);
  sgemm_kernel<64, 64, 32, 4, 4><<<dim3(8, 1), 256, 0, stream>>>(
      phrase, WcPt, nullptr, Xpt, BPc, HO, Rc, 0);
  pair_gemm_kernel<64, 64, 32, 4, 4, 2, HO><<<dim3(8, 16), 256, 0, stream>>>(
      vist, phrase, WcVPt, Xvt, Xpt, b1ct, hidnt, PAIRS2);
  layer2_t_kernel<<<PAIRS2 / 4, 256, 0, stream>>>(
      hidnt, simt_w2, simt_b2, regt_w2, regt_b2, simtlog, o_regt, PAIRS2);
  softmax16_kernel<<<BPc, 64, 0, stream>>>(simtlog, o_simt);
}

// Round 9
// 1561.810 us; speedup vs baseline: 1.4023x; 1.0065x over previous
//
#include <hip/hip_runtime.h>
#include <hip/hip_bf16.h>

// DetProposalVGHead on MI355X.
// fused = [v, p, v*p, v-p]  =>  fused@W1 = v@(Wa+Wd) + p@(Wb-Wd) + (v*p)@Wc
//
// Validated semantics (r5/r6/r7 GREEN): top-k = fp64 chain ordering with
// EPS=2.5e-7 tie-window resolved to LOWEST index. fp64 machinery unchanged.
// Round-9 = round-8 resubmit (r8 was an infra failure, kernel never ran):
//  * XOR-swizzled A-tile staging (kills the 8-way LDS write conflict, 3.15e7)
//  * split B-fragment mapping for TN=8 (kills the 4-way read conflict)
//  * layer-2 fused into pair_gemm-1 epilogue (shuffle-reduce + atomicAdd;
//    removes 64MB hidden traffic + one 16K-wave launch)
//  * defensive: output zeroing moved from hipMemsetAsync into prep_all_kernel.

namespace {

constexpr int Nc_   = 256;    // boxes
constexpr int Dc    = 2048;
constexpr int Rc    = 1024;
constexpr int TOPN  = 16;
constexpr int NCAND = 32;     // fp32 prescreen candidates per row
constexpr int HS    = 256;    // per-head hidden width
constexpr int HO    = 512;    // combined (sim|reg) hidden width
constexpr int BPc   = 64;     // B*P
constexpr int PAIRS1 = 16384; // B*P*N
constexpr int PAIRS2 = 1024;  // B*P*topN
constexpr int CPAIRS = BPc * NCAND; // 2048

__device__ __forceinline__ float  leaky01f(float x)  { return x > 0.f ? x : 0.01f * x; }
__device__ __forceinline__ double leaky01d(double x) { return x > 0.0 ? x : 0.01  * x; }

// A-tile LDS column swizzle: col = m ^ (8*((k>>2)&7)). Bijective, f4-safe
// (touches bits >=3 only), conflict-free staging writes + fragment reads.
__device__ __forceinline__ int aswz(int m, int k) { return m ^ (8 * ((k >> 2) & 7)); }

// ---------------------------------------------------------------------------
// fp64 GEMM: C64 = act(A @ W + bias). BM=32, BN=64, BK=16, 256 thr, TM=2 TN=4.
// (unchanged from r7 — conflict-free reads, validated)
// ---------------------------------------------------------------------------
template <typename TA, typename TW, bool LEAKY>
__global__ __launch_bounds__(256) void dg64_kernel(
    const TA* __restrict__ A, const TW* __restrict__ W, const float* __restrict__ bias,
    double* __restrict__ C64, int M, int N, int K)
{
  __shared__ double As[16][33];
  __shared__ double Bs[16][66];
  const int t = threadIdx.x, tx = t & 15, ty = t >> 4;
  const int row0 = blockIdx.y * 32, col0 = blockIdx.x * 64;
  double acc[2][4] = {};

  const int mm = t >> 3, kqa = (t & 7) * 2;
  const int kkb = t >> 4, nqb = (t & 15) * 4;

  for (int k0 = 0; k0 < K; k0 += 16) {
    {
      const TA* src = A + (size_t)(row0 + mm) * K + k0 + kqa;
      double v0, v1;
      if constexpr (sizeof(TA) == 4) {
        float2 f = *(const float2*)src; v0 = f.x; v1 = f.y;
      } else {
        double2 d = *(const double2*)src; v0 = d.x; v1 = d.y;
      }
      As[kqa][mm] = v0; As[kqa + 1][mm] = v1;
    }
    {
      const TW* src = W + (size_t)(k0 + kkb) * N + col0 + nqb;
      if constexpr (sizeof(TW) == 4) {
        float4 f = *(const float4*)src;
        Bs[kkb][nqb] = f.x; Bs[kkb][nqb + 1] = f.y;
        Bs[kkb][nqb + 2] = f.z; Bs[kkb][nqb + 3] = f.w;
      } else {
        double2 a = *(const double2*)src, b = *(const double2*)(src + 2);
        Bs[kkb][nqb] = a.x; Bs[kkb][nqb + 1] = a.y;
        Bs[kkb][nqb + 2] = b.x; Bs[kkb][nqb + 3] = b.y;
      }
    }
    __syncthreads();
#pragma unroll
    for (int kk = 0; kk < 16; ++kk) {
      double a[2], b[4];
#pragma unroll
      for (int i = 0; i < 2; ++i) a[i] = As[kk][ty * 2 + i];
#pragma unroll
      for (int j = 0; j < 4; ++j) b[j] = Bs[kk][tx + 16 * j];
#pragma unroll
      for (int i = 0; i < 2; ++i)
#pragma unroll
        for (int j = 0; j < 4; ++j) acc[i][j] = fma(a[i], b[j], acc[i][j]);
    }
    __syncthreads();
  }

#pragma unroll
  for (int i = 0; i < 2; ++i) {
    int r = row0 + ty * 2 + i;
#pragma unroll
    for (int j = 0; j < 4; ++j) {
      int c = col0 + tx + 16 * j;
      double v = acc[i][j];
      if (bias) v += (double)bias[c];
      if constexpr (LEAKY) v = leaky01d(v);
      C64[(size_t)r * N + c] = v;
    }
  }
}

// ---------------------------------------------------------------------------
// fp64 candidate pair GEMM (unchanged from r7)
// ---------------------------------------------------------------------------
__global__ __launch_bounds__(256) void pair64c_kernel(
    const double* __restrict__ vis, const float* __restrict__ phr,
    const double* __restrict__ W, const double* __restrict__ Xv,
    const double* __restrict__ Xp, const double* __restrict__ b1,
    const int* __restrict__ candn, double* __restrict__ H)
{
  __shared__ double As[16][33];
  __shared__ double Bs[16][66];
  const int t = threadIdx.x, tx = t & 15, ty = t >> 4;
  const int row0 = blockIdx.y * 32, col0 = blockIdx.x * 64;
  double acc[2][4] = {};

  const int mm = t >> 3, kqa = (t & 7) * 2;
  const int kkb = t >> 4, nqb = (t & 15) * 4;
  const int ms = row0 + mm, bps = ms >> 5;
  const int vrs = ((bps >> 4) << 8) | candn[ms], prs = bps;

  for (int k0 = 0; k0 < Rc; k0 += 16) {
    {
      double2 v = *(const double2*)(vis + (size_t)vrs * Rc + k0 + kqa);
      float2  p = *(const float2*)(phr + (size_t)prs * Rc + k0 + kqa);
      As[kqa][mm]     = v.x * (double)p.x;
      As[kqa + 1][mm] = v.y * (double)p.y;
    }
    {
      const double* src = W + (size_t)(k0 + kkb) * HS + col0 + nqb;
      double2 a = *(const double2*)src, b = *(const double2*)(src + 2);
      Bs[kkb][nqb] = a.x; Bs[kkb][nqb + 1] = a.y;
      Bs[kkb][nqb + 2] = b.x; Bs[kkb][nqb + 3] = b.y;
    }
    __syncthreads();
#pragma unroll
    for (int kk = 0; kk < 16; ++kk) {
      double a[2], b[4];
#pragma unroll
      for (int i = 0; i < 2; ++i) a[i] = As[kk][ty * 2 + i];
#pragma unroll
      for (int j = 0; j < 4; ++j) b[j] = Bs[kk][tx + 16 * j];
#pragma unroll
      for (int i = 0; i < 2; ++i)
#pragma unroll
        for (int j = 0; j < 4; ++j) acc[i][j] = fma(a[i], b[j], acc[i][j]);
    }
    __syncthreads();
  }

#pragma unroll
  for (int i = 0; i < 2; ++i) {
    int r = row0 + ty * 2 + i, bp = r >> 5;
    int vr = ((bp >> 4) << 8) | candn[r], pr = bp;
#pragma unroll
    for (int j = 0; j < 4; ++j) {
      int c = col0 + tx + 16 * j;
      double v = acc[i][j] + Xv[(size_t)vr * HS + c] + Xp[(size_t)pr * HS + c] + b1[c];
      H[(size_t)r * HS + c] = leaky01d(v);
    }
  }
}

// ---------------------------------------------------------------------------
// fp32 tiled GEMM with swizzled A staging: C = act(A@W + bias).
// ---------------------------------------------------------------------------
template <int BM, int BN, int BK, int TM, int TN>
__global__ __launch_bounds__(256) void sgemm_kernel(
    const float* __restrict__ A, const float* __restrict__ W,
    const float* __restrict__ bias, float* __restrict__ C,
    int M, int Nc, int K, int leaky)
{
  constexpr int THREADS = (BM / TM) * (BN / TN);
  static_assert(THREADS == 256, "block must be 256");
  __shared__ float As[BK][BM];
  __shared__ float Bs[BK][BN];

  const int t = threadIdx.x;
  const int tx = t % (BN / TN), ty = t / (BN / TN);
  const int row0 = blockIdx.y * BM, col0 = blockIdx.x * BN;
  float acc[TM][TN] = {};

  for (int k0 = 0; k0 < K; k0 += BK) {
    constexpr int AV = BM * BK / 4 / THREADS;
#pragma unroll
    for (int p_ = 0; p_ < AV; ++p_) {
      int f = p_ * THREADS + t;
      int mm = f / (BK / 4), kq = (f % (BK / 4)) * 4;
      float4 a4 = *(const float4*)(A + (size_t)(row0 + mm) * K + k0 + kq);
      int cs = aswz(mm, kq);        // swz constant across kq..kq+3
      As[kq + 0][cs] = a4.x; As[kq + 1][cs] = a4.y;
      As[kq + 2][cs] = a4.z; As[kq + 3][cs] = a4.w;
    }
    constexpr int BV = BK * BN / 4 / THREADS;
#pragma unroll
    for (int p_ = 0; p_ < BV; ++p_) {
      int f = p_ * THREADS + t;
      int nq = (f % (BN / 4)) * 4, kk = f / (BN / 4);
      *(float4*)&Bs[kk][nq] = *(const float4*)(W + (size_t)(k0 + kk) * Nc + col0 + nq);
    }
    __syncthreads();
#pragma unroll
    for (int kk = 0; kk < BK; ++kk) {
      float a[TM], bb[TN];
      int ab = aswz(ty * TM, kk);
#pragma unroll
      for (int i = 0; i < TM; i += 4) {
        float4 v = *(const float4*)&As[kk][ab + i];   // (ty*TM+i)^swz = base+i
        a[i] = v.x; a[i + 1] = v.y; a[i + 2] = v.z; a[i + 3] = v.w;
      }
#pragma unroll
      for (int j = 0; j < TN; j += 4) {
        float4 v = *(const float4*)&Bs[kk][tx * TN + j];
        bb[j] = v.x; bb[j + 1] = v.y; bb[j + 2] = v.z; bb[j + 3] = v.w;
      }
#pragma unroll
      for (int i = 0; i < TM; ++i)
#pragma unroll
        for (int j = 0; j < TN; ++j) acc[i][j] = fmaf(a[i], bb[j], acc[i][j]);
    }
    __syncthreads();
  }

#pragma unroll
  for (int i = 0; i < TM; ++i) {
    int r = row0 + ty * TM + i;
#pragma unroll
    for (int j = 0; j < TN; j += 4) {
      int c = col0 + tx * TN + j;
      float4 o;
      o.x = acc[i][j]; o.y = acc[i][j + 1]; o.z = acc[i][j + 2]; o.w = acc[i][j + 3];
      if (bias) {
        float4 bv = *(const float4*)(bias + c);
        o.x += bv.x; o.y += bv.y; o.z += bv.z; o.w += bv.w;
      }
      if (leaky) { o.x = leaky01f(o.x); o.y = leaky01f(o.y); o.z = leaky01f(o.z); o.w = leaky01f(o.w); }
      *(float4*)(C + (size_t)r * Nc + c) = o;
    }
  }
}

// ---------------------------------------------------------------------------
// fp32 pair GEMM. TN==8 uses split B-fragment (cols tx*4 and 64+tx*4).
// FUSE: layer-2 partial dots reduced over tx + atomicAdd (no Hout write).
// ---------------------------------------------------------------------------
template <int BM, int BN, int BK, int TM, int TN, int STAGE, int NCOL, bool FUSE>
__global__ __launch_bounds__(256) void pair_gemm_kernel(
    const float* __restrict__ vis, const float* __restrict__ phr,
    const float* __restrict__ Wvp, const float* __restrict__ Xv,
    const float* __restrict__ Xp, const float* __restrict__ b1c,
    float* __restrict__ Hout,
    const float* __restrict__ sw2, const float* __restrict__ sb2,
    const float* __restrict__ rw2, const float* __restrict__ rb2,
    float* __restrict__ simlog, float* __restrict__ rego)
{
  constexpr int THREADS = (BM / TM) * (BN / TN);
  static_assert(THREADS == 256, "block must be 256");
  __shared__ float As[BK][BM];
  __shared__ float Bs[BK][BN];

  const int t = threadIdx.x;
  const int tx = t % (BN / TN), ty = t / (BN / TN);
  const int row0 = blockIdx.y * BM, col0 = blockIdx.x * BN;
  float acc[TM][TN] = {};

  for (int k0 = 0; k0 < Rc; k0 += BK) {
    constexpr int AV = BM * BK / 4 / THREADS;
#pragma unroll
    for (int p_ = 0; p_ < AV; ++p_) {
      int f = p_ * THREADS + t;
      int mm = f / (BK / 4), kq = (f % (BK / 4)) * 4;
      int m = row0 + mm;
      int vr, pr;
      if (STAGE == 1) { int bp = m >> 8; pr = bp; vr = ((bp >> 4) << 8) | (m & 255); }
      else            { vr = m; pr = m >> 4; }
      float4 v4 = *(const float4*)(vis + (size_t)vr * Rc + k0 + kq);
      float4 p4 = *(const float4*)(phr + (size_t)pr * Rc + k0 + kq);
      int cs = aswz(mm, kq);
      As[kq + 0][cs] = v4.x * p4.x; As[kq + 1][cs] = v4.y * p4.y;
      As[kq + 2][cs] = v4.z * p4.z; As[kq + 3][cs] = v4.w * p4.w;
    }
    constexpr int BV = BK * BN / 4 / THREADS;
#pragma unroll
    for (int p_ = 0; p_ < BV; ++p_) {
      int f = p_ * THREADS + t;
      int nq = (f % (BN / 4)) * 4, kk = f / (BN / 4);
      *(float4*)&Bs[kk][nq] = *(const float4*)(Wvp + (size_t)(k0 + kk) * NCOL + col0 + nq);
    }
    __syncthreads();
#pragma unroll
    for (int kk = 0; kk < BK; ++kk) {
      float a[TM], bb[TN];
      int ab = aswz(ty * TM, kk);
#pragma unroll
      for (int i = 0; i < TM; i += 4) {
        float4 v = *(const float4*)&As[kk][ab + i];
        a[i] = v.x; a[i + 1] = v.y; a[i + 2] = v.z; a[i + 3] = v.w;
      }
      if constexpr (TN == 8) {
        float4 v0 = *(const float4*)&Bs[kk][tx * 4];
        float4 v1 = *(const float4*)&Bs[kk][64 + tx * 4];
        bb[0] = v0.x; bb[1] = v0.y; bb[2] = v0.z; bb[3] = v0.w;
        bb[4] = v1.x; bb[5] = v1.y; bb[6] = v1.z; bb[7] = v1.w;
      } else {
#pragma unroll
        for (int j = 0; j < TN; j += 4) {
          float4 v = *(const float4*)&Bs[kk][tx * TN + j];
          bb[j] = v.x; bb[j + 1] = v.y; bb[j + 2] = v.z; bb[j + 3] = v.w;
        }
      }
#pragma unroll
      for (int i = 0; i < TM; ++i)
#pragma unroll
        for (int j = 0; j < TN; ++j) acc[i][j] = fmaf(a[i], bb[j], acc[i][j]);
    }
    __syncthreads();
  }

  // column bases for this thread
  const int cA = col0 + tx * 4;            // j = 0..3
  const int cB = col0 + 64 + tx * 4;       // j = 4..7 (TN==8 only)

  // hoisted layer-2 weights (FUSE path)
  float4 wsA, wsB;
  float4 rwA[4], rwB[4];
  bool is_sim = false;
  if constexpr (FUSE) {
    is_sim = (col0 < 256);
    if (is_sim) {
      wsA = *(const float4*)(sw2 + cA);
      wsB = *(const float4*)(sw2 + cB);
    } else {
#pragma unroll
      for (int j = 0; j < 4; ++j) rwA[j] = *(const float4*)(rw2 + (size_t)(cA + j - 256) * 4);
#pragma unroll
      for (int j = 0; j < 4; ++j) rwB[j] = *(const float4*)(rw2 + (size_t)(cB + j - 256) * 4);
    }
  }

#pragma unroll
  for (int i = 0; i < TM; ++i) {
    int r = row0 + ty * TM + i;
    int vr, pr;
    if (STAGE == 1) { int bp = r >> 8; pr = bp; vr = ((bp >> 4) << 8) | (r & 255); }
    else            { vr = r; pr = r >> 4; }
    if constexpr (TN == 8) {
      float h[8];
      {
        float4 xv = *(const float4*)(Xv + (size_t)vr * NCOL + cA);
        float4 xp = *(const float4*)(Xp + (size_t)pr * NCOL + cA);
        float4 bv = *(const float4*)(b1c + cA);
        h[0] = leaky01f(acc[i][0] + xv.x + xp.x + bv.x);
        h[1] = leaky01f(acc[i][1] + xv.y + xp.y + bv.y);
        h[2] = leaky01f(acc[i][2] + xv.z + xp.z + bv.z);
        h[3] = leaky01f(acc[i][3] + xv.w + xp.w + bv.w);
      }
      {
        float4 xv = *(const float4*)(Xv + (size_t)vr * NCOL + cB);
        float4 xp = *(const float4*)(Xp + (size_t)pr * NCOL + cB);
        float4 bv = *(const float4*)(b1c + cB);
        h[4] = leaky01f(acc[i][4] + xv.x + xp.x + bv.x);
        h[5] = leaky01f(acc[i][5] + xv.y + xp.y + bv.y);
        h[6] = leaky01f(acc[i][6] + xv.z + xp.z + bv.z);
        h[7] = leaky01f(acc[i][7] + xv.w + xp.w + bv.w);
      }
      if constexpr (FUSE) {
        if (is_sim) {
          float part = h[0] * wsA.x + h[1] * wsA.y + h[2] * wsA.z + h[3] * wsA.w
                     + h[4] * wsB.x + h[5] * wsB.y + h[6] * wsB.z + h[7] * wsB.w;
#pragma unroll
          for (int off = 8; off; off >>= 1) part += __shfl_xor(part, off);
          if (tx == 0) {
            if (col0 == 0) part += sb2[0];
            atomicAdd(simlog + r, part);
          }
        } else {
          float p0 = 0, p1 = 0, p2 = 0, p3 = 0;
#pragma unroll
          for (int j = 0; j < 4; ++j) {
            p0 += h[j] * rwA[j].x; p1 += h[j] * rwA[j].y;
            p2 += h[j] * rwA[j].z; p3 += h[j] * rwA[j].w;
            p0 += h[j + 4] * rwB[j].x; p1 += h[j + 4] * rwB[j].y;
            p2 += h[j + 4] * rwB[j].z; p3 += h[j + 4] * rwB[j].w;
          }
#pragma unroll
          for (int off = 8; off; off >>= 1) {
            p0 += __shfl_xor(p0, off); p1 += __shfl_xor(p1, off);
            p2 += __shfl_xor(p2, off); p3 += __shfl_xor(p3, off);
          }
          if (tx == 0) {
            if (col0 == 256) { p0 += rb2[0]; p1 += rb2[1]; p2 += rb2[2]; p3 += rb2[3]; }
            atomicAdd(rego + (size_t)r * 4 + 0, p0);
            atomicAdd(rego + (size_t)r * 4 + 1, p1);
            atomicAdd(rego + (size_t)r * 4 + 2, p2);
            atomicAdd(rego + (size_t)r * 4 + 3, p3);
          }
        }
      } else {
        *(float4*)(Hout + (size_t)r * NCOL + cA) = make_float4(h[0], h[1], h[2], h[3]);
        *(float4*)(Hout + (size_t)r * NCOL + cB) = make_float4(h[4], h[5], h[6], h[7]);
      }
    } else {
#pragma unroll
      for (int j = 0; j < TN; j += 4) {
        int c = col0 + tx * TN + j;
        float4 xv = *(const float4*)(Xv + (size_t)vr * NCOL + c);
        float4 xp = *(const float4*)(Xp + (size_t)pr * NCOL + c);
        float4 bv = *(const float4*)(b1c + c);
        float4 o;
        o.x = leaky01f(acc[i][j]     + xv.x + xp.x + bv.x);
        o.y = leaky01f(acc[i][j + 1] + xv.y + xp.y + bv.y);
        o.z = leaky01f(acc[i][j + 2] + xv.z + xp.z + bv.z);
        o.w = leaky01f(acc[i][j + 3] + xv.w + xp.w + bv.w);
        *(float4*)(Hout + (size_t)r * NCOL + c) = o;
      }
    }
  }
}

// --- merged weight prep + output zeroing ------------------------------------
__global__ __launch_bounds__(256) void prep_all_kernel(
    const float* __restrict__ sim_w1, const float* __restrict__ sim_b1,
    const float* __restrict__ reg_w1, const float* __restrict__ reg_b1,
    const float* __restrict__ simt_w1, const float* __restrict__ simt_b1,
    const float* __restrict__ regt_w1, const float* __restrict__ regt_b1,
    double* __restrict__ WV64, double* __restrict__ WP64, double* __restrict__ WVP64,
    double* __restrict__ b64,
    float* __restrict__ W1V, float* __restrict__ W1P, float* __restrict__ W1VP,
    float* __restrict__ b1,
    float* __restrict__ WtV, float* __restrict__ WtP, float* __restrict__ WtVP,
    float* __restrict__ bt,
    float* __restrict__ zero_simlog, float* __restrict__ zero_rego)
{
  int bid = blockIdx.x;
  if (bid < 1024) {                         // fp64 sim head: Rc*HS
    int idx = bid * 256 + threadIdx.x;
    int r = idx >> 8, c = idx & 255;
    double wa = (double)sim_w1[(size_t)(0 * Rc + r) * 256 + c];
    double wb = (double)sim_w1[(size_t)(1 * Rc + r) * 256 + c];
    double wc = (double)sim_w1[(size_t)(2 * Rc + r) * 256 + c];
    double wd = (double)sim_w1[(size_t)(3 * Rc + r) * 256 + c];
    WV64[idx] = wa + wd; WP64[idx] = wb - wd; WVP64[idx] = wc;
    if (r == 0) b64[c] = (double)sim_b1[c];
  } else if (bid < 3072) {                  // stage-1 fp32 combined: Rc*HO
    int idx = (bid - 1024) * 256 + threadIdx.x;
    int r = idx >> 9, j = idx & (HO - 1);
    const float* w1 = (j < 256) ? sim_w1 : reg_w1;
    int c = j & 255;
    float wa = w1[(size_t)(0 * Rc + r) * 256 + c];
    float wb = w1[(size_t)(1 * Rc + r) * 256 + c];
    float wc = w1[(size_t)(2 * Rc + r) * 256 + c];
    float wd = w1[(size_t)(3 * Rc + r) * 256 + c];
    W1V[idx] = wa + wd; W1P[idx] = wb - wd; W1VP[idx] = wc;
    if (r == 0) b1[j] = (j < 256) ? sim_b1[c] : reg_b1[c];
  } else if (bid < 5120) {                  // stage-2 fp32 combined: Rc*HO
    int idx = (bid - 3072) * 256 + threadIdx.x;
    int r = idx >> 9, j = idx & (HO - 1);
    const float* w1 = (j < 256) ? simt_w1 : regt_w1;
    int c = j & 255;
    float wa = w1[(size_t)(0 * Rc + r) * 256 + c];
    float wb = w1[(size_t)(1 * Rc + r) * 256 + c];
    float wc = w1[(size_t)(2 * Rc + r) * 256 + c];
    float wd = w1[(size_t)(3 * Rc + r) * 256 + c];
    WtV[idx] = wa + wd; WtP[idx] = wb - wd; WtVP[idx] = wc;
    if (r == 0) bt[j] = (j < 256) ? simt_b1[c] : regt_b1[c];
  } else if (bid < 5184) {                  // zero simlog32: 16384 floats
    zero_simlog[(bid - 5120) * 256 + threadIdx.x] = 0.f;
  } else {                                  // zero o_reg: 65536 floats (256 blocks)
    zero_rego[(size_t)(bid - 5184) * 256 + threadIdx.x] = 0.f;
  }
}

// --- second layers ---------------------------------------------------------
__global__ __launch_bounds__(256) void layer2_t_kernel(
    const float* __restrict__ hidden,
    const float* __restrict__ sw2, const float* __restrict__ sb2,
    const float* __restrict__ rw2, const float* __restrict__ rb2,
    float* __restrict__ sim_logits, float* __restrict__ reg_out, int M)
{
  int wave = (blockIdx.x * blockDim.x + threadIdx.x) >> 6, lane = threadIdx.x & 63;
  if (wave >= M) return;
  const float* h = hidden + (size_t)wave * HO;
  float4 hs = *(const float4*)(h + lane * 4);
  float4 hr = *(const float4*)(h + 256 + lane * 4);
  float4 ws = *(const float4*)(sw2 + lane * 4);
  float s = hs.x * ws.x + hs.y * ws.y + hs.z * ws.z + hs.w * ws.w;
  float4 r0 = *(const float4*)(rw2 + (size_t)(lane * 4 + 0) * 4);
  float4 r1 = *(const float4*)(rw2 + (size_t)(lane * 4 + 1) * 4);
  float4 r2 = *(const float4*)(rw2 + (size_t)(lane * 4 + 2) * 4);
  float4 r3 = *(const float4*)(rw2 + (size_t)(lane * 4 + 3) * 4);
  float c0 = hr.x * r0.x + hr.y * r1.x + hr.z * r2.x + hr.w * r3.x;
  float c1 = hr.x * r0.y + hr.y * r1.y + hr.z * r2.y + hr.w * r3.y;
  float c2 = hr.x * r0.z + hr.y * r1.z + hr.z * r2.z + hr.w * r3.z;
  float c3 = hr.x * r0.w + hr.y * r1.w + hr.z * r2.w + hr.w * r3.w;
#pragma unroll
  for (int off = 32; off; off >>= 1) {
    s  += __shfl_xor(s, off);
    c0 += __shfl_xor(c0, off); c1 += __shfl_xor(c1, off);
    c2 += __shfl_xor(c2, off); c3 += __shfl_xor(c3, off);
  }
  if (lane == 0) {
    sim_logits[wave] = s + sb2[0];
    float4 o; o.x = c0 + rb2[0]; o.y = c1 + rb2[1]; o.z = c2 + rb2[2]; o.w = c3 + rb2[3];
    *(float4*)(reg_out + (size_t)wave * 4) = o;
  }
}

__global__ __launch_bounds__(256) void layer2_sim64_kernel(
    const double* __restrict__ h, const float* __restrict__ sw2,
    const float* __restrict__ sb2, double* __restrict__ out, int M)
{
  int wave = (blockIdx.x * blockDim.x + threadIdx.x) >> 6, lane = threadIdx.x & 63;
  if (wave >= M) return;
  const double* hr = h + (size_t)wave * HS + lane * 4;
  double2 h0 = *(const double2*)hr, h1 = *(const double2*)(hr + 2);
  float4 w = *(const float4*)(sw2 + lane * 4);
  double s = h0.x * (double)w.x + h0.y * (double)w.y + h1.x * (double)w.z + h1.y * (double)w.w;
#pragma unroll
  for (int off = 32; off; off >>= 1) s += __shfl_xor(s, off);
  if (lane == 0) out[wave] = s + (double)sb2[0];
}

// --- fp32 softmax + top-32 candidate superset -------------------------------
__global__ __launch_bounds__(64) void softmax_cand32_kernel(
    const float* __restrict__ logits, float* __restrict__ sim_out,
    int* __restrict__ candn)
{
  int row = blockIdx.x, lane = threadIdx.x;
  float v[4];
#pragma unroll
  for (int i = 0; i < 4; ++i) v[i] = logits[row * 256 + i * 64 + lane];
  float m = fmaxf(fmaxf(v[0], v[1]), fmaxf(v[2], v[3]));
#pragma unroll
  for (int off = 32; off; off >>= 1) m = fmaxf(m, __shfl_xor(m, off));
  float e[4], ssum = 0.f;
#pragma unroll
  for (int i = 0; i < 4; ++i) { e[i] = expf(v[i] - m); ssum += e[i]; }
#pragma unroll
  for (int off = 32; off; off >>= 1) ssum += __shfl_xor(ssum, off);
#pragma unroll
  for (int i = 0; i < 4; ++i)
    sim_out[row * 256 + i * 64 + lane] = e[i] / ssum;
  for (int it = 0; it < NCAND; ++it) {
    float bv = -3.0e38f; int bi = 0;
#pragma unroll
    for (int i = 0; i < 4; ++i)
      if (v[i] > bv) { bv = v[i]; bi = i * 64 + lane; }
#pragma unroll
    for (int off = 32; off; off >>= 1) {
      float ov = __shfl_xor(bv, off);
      int   oi = __shfl_xor(bi, off);
      if (ov > bv || (ov == bv && oi < bi)) { bv = ov; bi = oi; }
    }
    if (lane == 0) candn[row * NCAND + it] = bi;
    if ((bi & 63) == lane) v[bi >> 6] = -3.4e38f;
  }
}

// --- fp64+EPS top-16 over 32 candidates (validated r5/r6/r7 semantics) ------
__global__ __launch_bounds__(64) void topk_cand64_kernel(
    const double* __restrict__ clog, const int* __restrict__ candn,
    int* __restrict__ top_idx)
{
  int row = blockIdx.x, lane = threadIdx.x;
  double v = (lane < NCAND) ? clog[row * NCAND + lane] : -1.0e300;
  int    n = (lane < NCAND) ? candn[row * NCAND + lane] : (1 << 29);
  const double EPS = 2.5e-7;
  for (int it = 0; it < TOPN; ++it) {
    double vm = v;
#pragma unroll
    for (int off = 32; off; off >>= 1) vm = fmax(vm, __shfl_xor(vm, off));
    double thr = vm - EPS;
    int bn = (v >= thr) ? n : (1 << 30);
#pragma unroll
    for (int off = 32; off; off >>= 1) {
      int o = __shfl_xor(bn, off);
      if (o < bn) bn = o;
    }
    if (lane == 0) top_idx[row * TOPN + it] = bn;
    if (n == bn) v = -1.0e300;
  }
}

__global__ __launch_bounds__(64) void softmax16_kernel(
    const float* __restrict__ logits, float* __restrict__ out)
{
  int row = blockIdx.x, lane = threadIdx.x;
  float v = (lane < TOPN) ? logits[row * TOPN + lane] : -1e30f;
  float m = v;
#pragma unroll
  for (int off = 8; off; off >>= 1) m = fmaxf(m, __shfl_xor(m, off));
  float e = (lane < TOPN) ? expf(v - m) : 0.f;
  float s = e;
#pragma unroll
  for (int off = 8; off; off >>= 1) s += __shfl_xor(s, off);
  if (lane < TOPN) out[row * TOPN + lane] = e / s;
}

__global__ __launch_bounds__(256) void gather_kernel(
    const float* __restrict__ box, const int* __restrict__ top_idx,
    float* __restrict__ bf_top)
{
  int pr = blockIdx.x;
  int bp = pr >> 4, b = bp >> 4;
  int src = b * Nc_ + top_idx[pr];
  const float4* s = (const float4*)(box + (size_t)src * Dc);
  float4* d = (float4*)(bf_top + (size_t)pr * Dc);
  for (int i = threadIdx.x; i < Dc / 4; i += 256) d[i] = s[i];
}

}  // namespace

extern "C" void kernel_launch(void* const* d_in, const int* in_sizes, int n_in,
                              void* d_out, int out_size, void* d_ws, size_t ws_size,
                              hipStream_t stream) {
  const float* box    = (const float*)d_in[0];
  const float* phrase = (const float*)d_in[1];
  const float* ve_w1  = (const float*)d_in[2];
  const float* ve_b1  = (const float*)d_in[3];
  const float* ve_w2  = (const float*)d_in[4];
  const float* ve_b2  = (const float*)d_in[5];
  const float* sim_w1 = (const float*)d_in[6];
  const float* sim_b1 = (const float*)d_in[7];
  const float* sim_w2 = (const float*)d_in[8];
  const float* sim_b2 = (const float*)d_in[9];
  const float* reg_w1 = (const float*)d_in[10];
  const float* reg_b1 = (const float*)d_in[11];
  const float* reg_w2 = (const float*)d_in[12];
  const float* reg_b2 = (const float*)d_in[13];
  const float* vet_w1 = (const float*)d_in[14];
  const float* vet_b1 = (const float*)d_in[15];
  const float* vet_w2 = (const float*)d_in[16];
  const float* vet_b2 = (const float*)d_in[17];
  const float* simt_w1 = (const float*)d_in[18];
  const float* simt_b1 = (const float*)d_in[19];
  const float* simt_w2 = (const float*)d_in[20];
  const float* simt_b2 = (const float*)d_in[21];
  const float* regt_w1 = (const float*)d_in[22];
  const float* regt_b1 = (const float*)d_in[23];
  const float* regt_w2 = (const float*)d_in[24];
  const float* regt_b2 = (const float*)d_in[25];

  float* out = (float*)d_out;
  float* o_sim  = out;                 // [16384]
  float* o_reg  = out + PAIRS1;        // [65536]
  float* o_simt = out + 81920;         // [1024]
  float* o_regt = out + 82944;         // [4096]

  // --- workspace layout (peak ~46.5 MB; proven budget >= 52.5) ---
  constexpr size_t MB = 1u << 20;
  char* w = (char*)d_ws;
  double* WcV64  = (double*)(w + 0 * MB);   // 2MB
  double* WcP64  = (double*)(w + 2 * MB);   // 2MB
  double* WcVP64 = (double*)(w + 4 * MB);   // 2MB
  float*  Wc1V   = (float*)(w + 6 * MB);    // 2MB [1024][512]
  float*  Wc1P   = (float*)(w + 8 * MB);    // 2MB
  float*  Wc1VP  = (float*)(w + 10 * MB);   // 2MB
  // small block @12MB
  char* sm = w + 12 * MB;
  double* b1c64    = (double*)(sm + 0);              // 2KB
  float*  b1c1     = (float*) (sm + 4096);           // 2KB
  float*  b1ct     = (float*) (sm + 8192);           // 2KB
  int*    candn    = (int*)   (sm + 12288);          // 8KB
  double* clog64   = (double*)(sm + 24576);          // 16KB
  int*    topidx   = (int*)   (sm + 40960);          // 4KB
  float*  simtlog  = (float*) (sm + 45056);          // 4KB
  float*  simlog32 = (float*) (sm + 65536);          // 64KB
  float*  Xp32     = (float*) (sm + 131072);         // 128KB [64][512]
  double* Xp64     = (double*)(sm + 262144);         // 128KB [64][256]
  float*  Xpt      = (float*) (sm + 393216);         // 128KB [64][512]
  // region @12.5MB
  float*  H1_32 = (float*)(w + 12 * MB + 524288);    // 4MB (P1)
  float*  vis32 = (float*)(w + 16 * MB + 524288);    // 4MB (P1)
  double* vis64 = (double*)(w + 12 * MB + 524288);   // 8MB (P2; P1 temps dead)
  char* big = w + 20 * MB + 524288;
  double* H64   = (double*)(big);                    // 8MB  (P2)
  float*  Xv32  = (float*)(big + 8 * MB);            // 2MB  (P1)
  double* Xv64  = (double*)(big + 8 * MB);           // 2MB  (P2, Xv32 dead)
  double* H2    = (double*)(big + 10 * MB);          // 4MB  (P2)
  float*  bftop = (float*)(big);                     // 8MB  (P3, H64 dead)
  float*  H1t   = (float*)(big + 8 * MB);            // 4MB  (P3)
  float*  vist  = (float*)(big + 12 * MB);           // 4MB  (P3)
  float*  Xvt   = (float*)(big + 16 * MB);           // 2MB  (P3)
  float*  hidnt = (float*)(big + 18 * MB);           // 2MB  (P3)
  float*  WcVt  = (float*)(big + 20 * MB);           // 2MB  (prep-time, read P3)
  float*  WcPt  = (float*)(big + 22 * MB);           // 2MB
  float*  WcVPt = (float*)(big + 24 * MB);           // 2MB

  // ---- P1: fp32 value path (o_sim, o_reg) + candidate prescreen ----
  prep_all_kernel<<<5440, 256, 0, stream>>>(
      sim_w1, sim_b1, reg_w1, reg_b1, simt_w1, simt_b1, regt_w1, regt_b1,
      WcV64, WcP64, WcVP64, b1c64, Wc1V, Wc1P, Wc1VP, b1c1, WcVt, WcPt, WcVPt, b1ct,
      simlog32, o_reg);
  sgemm_kernel<64, 64, 32, 4, 4><<<dim3(16, 16), 256, 0, stream>>>(
      box, ve_w1, ve_b1, H1_32, 1024, Rc, Dc, 1);
  sgemm_kernel<64, 64, 32, 4, 4><<<dim3(16, 16), 256, 0, stream>>>(
      H1_32, ve_w2, ve_b2, vis32, 1024, Rc, Rc, 0);
  sgemm_kernel<64, 64, 32, 4, 4><<<dim3(8, 16), 256, 0, stream>>>(
      vis32, Wc1V, nullptr, Xv32, 1024, HO, Rc, 0);
  sgemm_kernel<64, 64, 32, 4, 4><<<dim3(8, 1), 256, 0, stream>>>(
      phrase, Wc1P, nullptr, Xp32, BPc, HO, Rc, 0);
  pair_gemm_kernel<128, 128, 32, 8, 8, 1, HO, true><<<dim3(4, 128), 256, 0, stream>>>(
      vis32, phrase, Wc1VP, Xv32, Xp32, b1c1, nullptr,
      sim_w2, sim_b2, reg_w2, reg_b2, simlog32, o_reg);
  softmax_cand32_kernel<<<BPc, 64, 0, stream>>>(simlog32, o_sim, candn);

  // ---- P2: fp64 ranking chain on candidates (validated EPS semantics) ----
  dg64_kernel<float, float, true><<<dim3(16, 32), 256, 0, stream>>>(
      box, ve_w1, ve_b1, H64, 1024, Rc, Dc);
  dg64_kernel<double, float, false><<<dim3(16, 32), 256, 0, stream>>>(
      H64, ve_w2, ve_b2, vis64, 1024, Rc, Rc);
  dg64_kernel<double, double, false><<<dim3(4, 32), 256, 0, stream>>>(
      vis64, WcV64, nullptr, Xv64, 1024, HS, Rc);
  dg64_kernel<float, double, false><<<dim3(4, 2), 256, 0, stream>>>(
      phrase, WcP64, nullptr, Xp64, BPc, HS, Rc);
  pair64c_kernel<<<dim3(4, CPAIRS / 32), 256, 0, stream>>>(
      vis64, phrase, WcVP64, Xv64, Xp64, b1c64, candn, H2);
  layer2_sim64_kernel<<<CPAIRS / 4, 256, 0, stream>>>(
      H2, sim_w2, sim_b2, clog64, CPAIRS);
  topk_cand64_kernel<<<BPc, 64, 0, stream>>>(clog64, candn, topidx);

  // ---- P3: stage 2 (fp32) ----
  gather_kernel<<<PAIRS2, 256, 0, stream>>>(box, topidx, bftop);
  sgemm_kernel<64, 64, 32, 4, 4><<<dim3(16, 16), 256, 0, stream>>>(
      bftop, vet_w1, vet_b1, H1t, 1024, Rc, Dc, 1);
  sgemm_kernel<64, 64, 32, 4, 4><<<dim3(16, 16), 256, 0, stream>>>(
      H1t, vet_w2, vet_b2, vist, 1024, Rc, Rc, 0);
  sgemm_kernel<64, 64, 32, 4, 4><<<dim3(8, 16), 256, 0, stream>>>(
      vist, WcVt, nullptr, Xvt, 1024, HO, Rc, 0);
  sgemm_kernel<64, 64, 32, 4, 4><<<dim3(8, 1), 256, 0, stream>>>(
      phrase, WcPt, nullptr, Xpt, BPc, HO, Rc, 0);
  pair_gemm_kernel<64, 64, 32, 4, 4, 2, HO, false><<<dim3(8, 16), 256, 0, stream>>>(
      vist, phrase, WcVPt, Xvt, Xpt, b1ct, hidnt,
      nullptr, nullptr, nullptr, nullptr, nullptr, nullptr);
  layer2_t_kernel<<<PAIRS2 / 4, 256, 0, stream>>>(
      hidnt, simt_w2, simt_b2, regt_w2, regt_b2, simtlog, o_regt, PAIRS2);
  softmax16_kernel<<<BPc, 64, 0, stream>>>(simtlog, o_simt);
}